// Round 1
// baseline (1123.089 us; speedup 1.0000x reference)
//
#include <hip/hip_runtime.h>
#include <hip/hip_bf16.h>
#include <math.h>

#define B 16
#define N 600
#define DIM 128
#define HEADS 8
#define DH 32
#define INNER 256
#define D3 384
#define NC_H (D3*INNER)   /* 98304 */
#define NC_O (INNER*DIM)  /* 32768 */

// ---------------- ws layout (float offsets) ----------------
// t2 : 0        .. 6144         [16][384]
// s2 : 6144     .. 10240        [16][256]
// h  : 10240    .. 1583104      [16][98304]  (qkvw after softmax, in place)
// ow : 1583104  .. 2107392      [16][32768]  (softmaxed in place)
// q  : 2107392  .. 4564992      [16][8][600][32]
// k  : 4564992  .. 7022592
// v  : 7022592  .. 9480192
// ao : 9480192  .. 11937792     [16][600][256]
// t1 : 11937792 .. 11943936     [16][384]
// s1 : 11943936 .. 11948032     [16][256]
// total 11,948,032 floats = 47.8 MB

__global__ void k_chain1(const float* __restrict__ resolution,
                         const float* __restrict__ framerate,
                         const float* __restrict__ W1, const float* __restrict__ b1,
                         const float* __restrict__ V1, const float* __restrict__ c1,
                         float* __restrict__ t1, float* __restrict__ s1)
{
    __shared__ float fr[B], re[B];
    int j = threadIdx.x;   // 384 threads
    if (j < B) { fr[j] = framerate[j]; re[j] = resolution[j]; }
    __syncthreads();
    {
        float w0 = W1[j], w1 = W1[D3 + j], bb = b1[j];
        for (int b = 0; b < B; ++b) t1[b*D3 + j] = fr[b]*w0 + re[b]*w1 + bb;
    }
    if (j < INNER) {
        float w0 = V1[j], w1 = V1[INNER + j], bb = c1[j];
        for (int b = 0; b < B; ++b) s1[b*INNER + j] = fr[b]*w0 + re[b]*w1 + bb;
    }
}

__global__ void k_chain2(const float* __restrict__ t1, const float* __restrict__ s1,
                         const float* __restrict__ W2, const float* __restrict__ b2,
                         const float* __restrict__ V2, const float* __restrict__ c2,
                         float* __restrict__ t2, float* __restrict__ s2)
{
    // blocks 0..23 -> t2 (16*384 outputs); blocks 24..39 -> s2 (16*256 outputs)
    __shared__ float in_s[B*D3];
    int bid = blockIdx.x, tid = threadIdx.x;
    if (bid < 24) {
        for (int i = tid; i < B*D3; i += 256) in_s[i] = t1[i];
        __syncthreads();
        int flat = bid*256 + tid;           // = b*384 + j
        int b = flat / D3, j = flat - b*D3;
        float acc = b2[j];
        #pragma unroll 4
        for (int kk = 0; kk < D3; ++kk)
            acc = fmaf(in_s[b*D3 + kk], W2[kk*D3 + j], acc);
        t2[flat] = acc;
    } else {
        for (int i = tid; i < B*INNER; i += 256) in_s[i] = s1[i];
        __syncthreads();
        int flat = (bid - 24)*256 + tid;    // = b*256 + j
        int b = flat / INNER, j = flat - b*INNER;
        float acc = c2[j];
        #pragma unroll 4
        for (int kk = 0; kk < INNER; ++kk)
            acc = fmaf(in_s[b*INNER + kk], V2[kk*INNER + j], acc);
        s2[flat] = acc;
    }
}

template<int K, int NC>
__global__ void k_hyper(const float* __restrict__ tin, const float* __restrict__ W,
                        const float* __restrict__ bias, float* __restrict__ out)
{
    __shared__ float ts[B*K];
    int tid = threadIdx.x;
    for (int i = tid; i < B*K; i += 256) ts[i] = tin[i];
    __syncthreads();
    int col = blockIdx.x*256 + tid;
    float bb = bias[col];
    float acc[B];
    #pragma unroll
    for (int b = 0; b < B; ++b) acc[b] = bb;
    #pragma unroll 8
    for (int kk = 0; kk < K; ++kk) {
        float w = W[(size_t)kk*NC + col];
        #pragma unroll
        for (int b = 0; b < B; ++b) acc[b] = fmaf(ts[b*K + kk], w, acc[b]);
    }
    #pragma unroll
    for (int b = 0; b < B; ++b) out[(size_t)b*NC + col] = acc[b];
}

// softmax along the R-axis of data[b][R][CPB] (stride CPB between elements)
template<int R, int CPB>
__global__ void k_softmax_col(float* __restrict__ data)
{
    int gid = blockIdx.x*256 + threadIdx.x;
    int b = gid / CPB, c = gid - b*CPB;
    float* p = data + (size_t)b*R*CPB + c;
    float m = -1e30f;
    for (int r = 0; r < R; ++r) m = fmaxf(m, p[(size_t)r*CPB]);
    float s = 0.f;
    for (int r = 0; r < R; ++r) s += __expf(p[(size_t)r*CPB] - m);
    float inv = 1.f/s;
    for (int r = 0; r < R; ++r) p[(size_t)r*CPB] = __expf(p[(size_t)r*CPB] - m)*inv;
}

__global__ __launch_bounds__(768) void k_proj(const float* __restrict__ x,
                                              const float* __restrict__ qkvw,
                                              float* __restrict__ q, float* __restrict__ k,
                                              float* __restrict__ v)
{
    __shared__ float xs[24*DIM];
    int b = blockIdx.x / 25, t0 = (blockIdx.x % 25)*24;
    int tid = threadIdx.x;
    const float* xp = x + ((size_t)b*N + t0)*DIM;
    for (int i = tid; i < 24*DIM; i += 768) xs[i] = xp[i];
    __syncthreads();
    float acc[24];
    #pragma unroll
    for (int r = 0; r < 24; ++r) acc[r] = 0.f;
    const float* wp = qkvw + (size_t)b*NC_H + tid;
    #pragma unroll 4
    for (int d = 0; d < DIM; ++d) {
        float w = wp[(size_t)d*768];
        #pragma unroll
        for (int r = 0; r < 24; ++r) acc[r] = fmaf(xs[r*DIM + d], w, acc[r]);
    }
    int which = tid >> 8;
    int e = tid & 255;
    int hh = e >> 5, dh = e & 31;
    float* outp = (which == 0 ? q : (which == 1 ? k : v));
    outp += ((size_t)(b*HEADS + hh)*N + t0)*DH + dh;
    #pragma unroll
    for (int r = 0; r < 24; ++r) outp[r*DH] = acc[r];
}

// flash attention, f32 vector ALU.  4 waves/block, 2 q-rows per wave,
// lane = key within a 64-key tile.  mask applied post-softmax.
__global__ __launch_bounds__(256) void k_attn(const float* __restrict__ q,
                                              const float* __restrict__ k,
                                              const float* __restrict__ v,
                                              const float* __restrict__ mask,
                                              float* __restrict__ ao)
{
    __shared__ float smem[4*2112];   // staging: klds=smem[0:2112], vlds=smem[2112:4224]; merge: 4x2112
    __shared__ float qs[8*DH];
    float* klds = smem;
    float* vlds = smem + 2112;

    int bid = blockIdx.x;
    int qt = bid % 75;
    int h  = (bid / 75) & 7;
    int b  = bid / 600;
    int tid = threadIdx.x;
    int wave = tid >> 6, lane = tid & 63;
    size_t bh = (size_t)(b*HEADS + h)*N;
    const float* Kb = k + bh*DH;
    const float* Vb = v + bh*DH;
    int row0 = qt*8;

    if (tid < 8*DH) qs[tid] = q[(bh + row0)*DH + tid];
    __syncthreads();

    int r0 = wave*2, r1 = wave*2 + 1;
    float q0[DH], q1[DH];
    #pragma unroll
    for (int d = 0; d < DH; ++d) { q0[d] = qs[r0*DH + d]; q1[d] = qs[r1*DH + d]; }
    const float* mp0 = mask + ((size_t)b*N + (row0 + r0))*N;
    const float* mp1 = mask + ((size_t)b*N + (row0 + r1))*N;

    float M0 = -1e30f, S0 = 0.f, M1 = -1e30f, S1 = 0.f;
    float acc0[DH], acc1[DH];
    #pragma unroll
    for (int d = 0; d < DH; ++d) { acc0[d] = 0.f; acc1[d] = 0.f; }

    const float scale = 0.17677669529663687f;  // 32^-0.5
    for (int k0 = 0; k0 < N; k0 += 64) {
        int nk = N - k0; if (nk > 64) nk = 64;
        __syncthreads();
        for (int i = tid; i < 64*DH; i += 256) {
            int r = i >> 5, d = i & 31;
            int src = (r < nk) ? ((k0 + r)*DH + d) : d;
            klds[r*33 + d] = Kb[src];
            vlds[r*33 + d] = Vb[src];
        }
        __syncthreads();
        bool valid = lane < nk;
        int m = k0 + (valid ? lane : 0);
        float mk0 = mp0[m], mk1 = mp1[m];
        float dot0 = 0.f, dot1 = 0.f;
        #pragma unroll
        for (int d = 0; d < DH; ++d) {
            float kd = klds[lane*33 + d];
            dot0 = fmaf(kd, q0[d], dot0);
            dot1 = fmaf(kd, q1[d], dot1);
        }
        dot0 *= scale; dot1 *= scale;
        if (dot0 > M0 + 8.f) {              // defer-max: rare after tile 0
            float sc = __expf(M0 - dot0);
            S0 *= sc;
            #pragma unroll
            for (int d = 0; d < DH; ++d) acc0[d] *= sc;
            M0 = dot0;
        }
        if (dot1 > M1 + 8.f) {
            float sc = __expf(M1 - dot1);
            S1 *= sc;
            #pragma unroll
            for (int d = 0; d < DH; ++d) acc1[d] *= sc;
            M1 = dot1;
        }
        float e0 = valid ? __expf(dot0 - M0) : 0.f;
        float e1 = valid ? __expf(dot1 - M1) : 0.f;
        S0 += e0; S1 += e1;                 // denominator WITHOUT mask
        float w0 = e0*mk0, w1 = e1*mk1;     // numerator WITH mask
        #pragma unroll
        for (int d = 0; d < DH; ++d) {
            float vd = vlds[lane*33 + d];
            acc0[d] = fmaf(w0, vd, acc0[d]);
            acc1[d] = fmaf(w1, vd, acc1[d]);
        }
    }

    __syncthreads();   // done with klds/vlds staging; reuse all of smem for merge
    float* wbuf = smem + wave*2112;   // [64][33] per wave
    int dd = lane & 31, half = lane >> 5;

    {   // row 0 merge
        float Ml = M0;
        float M = M0, S = S0;
        #pragma unroll
        for (int off = 32; off > 0; off >>= 1) {
            float Mo = __shfl_xor(M, off);
            float So = __shfl_xor(S, off);
            float Mn = fmaxf(M, Mo);
            S = S*__expf(M - Mn) + So*__expf(Mo - Mn);
            M = Mn;
        }
        float scl = __expf(Ml - M) / S;
        #pragma unroll
        for (int d = 0; d < DH; ++d) wbuf[lane*33 + d] = acc0[d]*scl;
        __syncthreads();
        float sum = 0.f;
        for (int l = 0; l < 32; ++l) sum += wbuf[(half*32 + l)*33 + dd];
        sum += __shfl_xor(sum, 32);
        if (lane < 32) {
            float* o = ao + ((size_t)b*N + (row0 + r0))*INNER + h*DH;
            o[lane] = sum;
        }
        __syncthreads();
    }
    {   // row 1 merge
        float Ml = M1;
        float M = M1, S = S1;
        #pragma unroll
        for (int off = 32; off > 0; off >>= 1) {
            float Mo = __shfl_xor(M, off);
            float So = __shfl_xor(S, off);
            float Mn = fmaxf(M, Mo);
            S = S*__expf(M - Mn) + So*__expf(Mo - Mn);
            M = Mn;
        }
        float scl = __expf(Ml - M) / S;
        #pragma unroll
        for (int d = 0; d < DH; ++d) wbuf[lane*33 + d] = acc1[d]*scl;
        __syncthreads();
        float sum = 0.f;
        for (int l = 0; l < 32; ++l) sum += wbuf[(half*32 + l)*33 + dd];
        sum += __shfl_xor(sum, 32);
        if (lane < 32) {
            float* o = ao + ((size_t)b*N + (row0 + r1))*INNER + h*DH;
            o[lane] = sum;
        }
    }
}

__global__ __launch_bounds__(128) void k_final(const float* __restrict__ ao,
                                               const float* __restrict__ ow,
                                               float* __restrict__ out)
{
    __shared__ float os[24*INNER];
    int b = blockIdx.x / 25, t0 = (blockIdx.x % 25)*24;
    int tid = threadIdx.x;
    const float* ap = ao + ((size_t)b*N + t0)*INNER;
    for (int i = tid; i < 24*INNER; i += 128) os[i] = ap[i];
    __syncthreads();
    float acc[24];
    #pragma unroll
    for (int r = 0; r < 24; ++r) acc[r] = 0.f;
    const float* wp = ow + (size_t)b*NC_O + tid;
    #pragma unroll 4
    for (int i = 0; i < INNER; ++i) {
        float w = wp[(size_t)i*DIM];
        #pragma unroll
        for (int r = 0; r < 24; ++r) acc[r] = fmaf(os[r*INNER + i], w, acc[r]);
    }
    float* op = out + ((size_t)b*N + t0)*DIM + tid;
    #pragma unroll
    for (int r = 0; r < 24; ++r) op[r*DIM] = acc[r];
}

extern "C" void kernel_launch(void* const* d_in, const int* in_sizes, int n_in,
                              void* d_out, int out_size, void* d_ws, size_t ws_size,
                              hipStream_t stream)
{
    const float* x          = (const float*)d_in[0];
    const float* mask       = (const float*)d_in[1];
    const float* resolution = (const float*)d_in[2];
    const float* framerate  = (const float*)d_in[3];
    const float* W1 = (const float*)d_in[4];
    const float* b1 = (const float*)d_in[5];
    const float* W2 = (const float*)d_in[6];
    const float* b2 = (const float*)d_in[7];
    const float* W3 = (const float*)d_in[8];
    const float* b3 = (const float*)d_in[9];
    const float* V1 = (const float*)d_in[10];
    const float* c1 = (const float*)d_in[11];
    const float* V2 = (const float*)d_in[12];
    const float* c2 = (const float*)d_in[13];
    const float* V3 = (const float*)d_in[14];
    const float* c3 = (const float*)d_in[15];

    float* ws = (float*)d_ws;
    float* t2 = ws;
    float* s2 = ws + 6144;
    float* h  = ws + 10240;
    float* ow = ws + 1583104;
    float* q  = ws + 2107392;
    float* k  = ws + 4564992;
    float* v  = ws + 7022592;
    float* ao = ws + 9480192;
    float* t1 = ws + 11937792;
    float* s1 = ws + 11943936;
    float* out = (float*)d_out;

    hipLaunchKernelGGL(k_chain1, dim3(1), dim3(384), 0, stream,
                       resolution, framerate, W1, b1, V1, c1, t1, s1);
    hipLaunchKernelGGL(k_chain2, dim3(40), dim3(256), 0, stream,
                       t1, s1, W2, b2, V2, c2, t2, s2);
    hipLaunchKernelGGL((k_hyper<D3, NC_H>), dim3(NC_H/256), dim3(256), 0, stream,
                       t2, W3, b3, h);
    hipLaunchKernelGGL((k_hyper<INNER, NC_O>), dim3(NC_O/256), dim3(256), 0, stream,
                       s2, V3, c3, ow);
    hipLaunchKernelGGL((k_softmax_col<DIM, 3*INNER>), dim3(B*3*INNER/256), dim3(256), 0, stream, h);
    hipLaunchKernelGGL((k_softmax_col<INNER, DIM>), dim3(B*DIM/256), dim3(256), 0, stream, ow);
    hipLaunchKernelGGL(k_proj, dim3(B*25), dim3(768), 0, stream, x, h, q, k, v);
    hipLaunchKernelGGL(k_attn, dim3(B*HEADS*75), dim3(256), 0, stream, q, k, v, mask, ao);
    hipLaunchKernelGGL(k_final, dim3(B*25), dim3(128), 0, stream, ao, ow, out);
}

// Round 2
// 938.024 us; speedup vs baseline: 1.1973x; 1.1973x over previous
//
#include <hip/hip_runtime.h>
#include <hip/hip_bf16.h>
#include <math.h>

#define B 16
#define N 600
#define DIM 128
#define HEADS 8
#define DH 32
#define INNER 256
#define D3 384
#define NC_H (D3*INNER)   /* 98304 */
#define NC_O (INNER*DIM)  /* 32768 */

// ---------------- ws layout (float offsets) ----------------
// t2 : 0        .. 6144         [16][384]
// s2 : 6144     .. 10240        [16][256]
// h  : 10240    .. 1583104      [16][98304]  (qkvw after softmax, in place)
// ow : 1583104  .. 2107392      [16][32768]  (softmaxed in place)
// q  : 2107392  .. 4564992      [16][8][600][32]
// k  : 4564992  .. 7022592
// v  : 7022592  .. 9480192
// ao : 9480192  .. 11937792     [16][600][256]
// t1 : 11937792 .. 11943936     [16][384]
// s1 : 11943936 .. 11948032     [16][256]

__global__ void k_chain1(const float* __restrict__ resolution,
                         const float* __restrict__ framerate,
                         const float* __restrict__ W1, const float* __restrict__ b1,
                         const float* __restrict__ V1, const float* __restrict__ c1,
                         float* __restrict__ t1, float* __restrict__ s1)
{
    __shared__ float fr[B], re[B];
    int j = threadIdx.x;   // 384 threads
    if (j < B) { fr[j] = framerate[j]; re[j] = resolution[j]; }
    __syncthreads();
    {
        float w0 = W1[j], w1 = W1[D3 + j], bb = b1[j];
        for (int b = 0; b < B; ++b) t1[b*D3 + j] = fr[b]*w0 + re[b]*w1 + bb;
    }
    if (j < INNER) {
        float w0 = V1[j], w1 = V1[INNER + j], bb = c1[j];
        for (int b = 0; b < B; ++b) s1[b*INNER + j] = fr[b]*w0 + re[b]*w1 + bb;
    }
}

__global__ void k_chain2(const float* __restrict__ t1, const float* __restrict__ s1,
                         const float* __restrict__ W2, const float* __restrict__ b2,
                         const float* __restrict__ V2, const float* __restrict__ c2,
                         float* __restrict__ t2, float* __restrict__ s2)
{
    __shared__ float in_s[B*D3];
    int bid = blockIdx.x, tid = threadIdx.x;
    if (bid < 24) {
        for (int i = tid; i < B*D3; i += 256) in_s[i] = t1[i];
        __syncthreads();
        int flat = bid*256 + tid;
        int b = flat / D3, j = flat - b*D3;
        float acc = b2[j];
        #pragma unroll 4
        for (int kk = 0; kk < D3; ++kk)
            acc = fmaf(in_s[b*D3 + kk], W2[kk*D3 + j], acc);
        t2[flat] = acc;
    } else {
        for (int i = tid; i < B*INNER; i += 256) in_s[i] = s1[i];
        __syncthreads();
        int flat = (bid - 24)*256 + tid;
        int b = flat / INNER, j = flat - b*INNER;
        float acc = c2[j];
        #pragma unroll 4
        for (int kk = 0; kk < INNER; ++kk)
            acc = fmaf(in_s[b*INNER + kk], V2[kk*INNER + j], acc);
        s2[flat] = acc;
    }
}

template<int K, int NC>
__global__ void k_hyper(const float* __restrict__ tin, const float* __restrict__ W,
                        const float* __restrict__ bias, float* __restrict__ out)
{
    __shared__ float ts[B*K];
    int tid = threadIdx.x;
    for (int i = tid; i < B*K; i += 256) ts[i] = tin[i];
    __syncthreads();
    int col = blockIdx.x*256 + tid;
    float bb = bias[col];
    float acc[B];
    #pragma unroll
    for (int b = 0; b < B; ++b) acc[b] = bb;
    #pragma unroll 8
    for (int kk = 0; kk < K; ++kk) {
        float w = W[(size_t)kk*NC + col];
        #pragma unroll
        for (int b = 0; b < B; ++b) acc[b] = fmaf(ts[b*K + kk], w, acc[b]);
    }
    #pragma unroll
    for (int b = 0; b < B; ++b) out[(size_t)b*NC + col] = acc[b];
}

// softmax along R-axis of data[b][R][CPB]; COLS*GROUPS = 256 threads
template<int R, int CPB, int COLS, int GROUPS>
__global__ __launch_bounds__(256) void k_softmax2(float* __restrict__ data)
{
    constexpr int RPT = R / GROUPS;
    __shared__ float red[GROUPS][COLS];
    int tid = threadIdx.x;
    int col = tid % COLS, g = tid / COLS;
    int nb = CPB / COLS;
    int b = blockIdx.x / nb, cb = blockIdx.x % nb;
    float* p = data + (size_t)b*R*CPB + (size_t)g*RPT*CPB + cb*COLS + col;
    float vals[RPT];
    float m = -1e30f;
    #pragma unroll 4
    for (int r = 0; r < RPT; ++r) { vals[r] = p[(size_t)r*CPB]; m = fmaxf(m, vals[r]); }
    red[g][col] = m;
    __syncthreads();
    float M = red[0][col];
    #pragma unroll
    for (int gg = 1; gg < GROUPS; ++gg) M = fmaxf(M, red[gg][col]);
    __syncthreads();
    float s = 0.f;
    #pragma unroll 4
    for (int r = 0; r < RPT; ++r) { vals[r] = __expf(vals[r] - M); s += vals[r]; }
    red[g][col] = s;
    __syncthreads();
    float S = 0.f;
    #pragma unroll
    for (int gg = 0; gg < GROUPS; ++gg) S += red[gg][col];
    float inv = 1.f / S;
    #pragma unroll 4
    for (int r = 0; r < RPT; ++r) p[(size_t)r*CPB] = vals[r] * inv;
}

__global__ __launch_bounds__(768) void k_proj(const float* __restrict__ x,
                                              const float* __restrict__ qkvw,
                                              float* __restrict__ q, float* __restrict__ k,
                                              float* __restrict__ v)
{
    __shared__ float4 xs4[24*32];
    int b = blockIdx.x / 25, t0 = (blockIdx.x % 25)*24;
    int tid = threadIdx.x;
    const float4* xp4 = (const float4*)(x + ((size_t)b*N + t0)*DIM);
    xs4[tid] = xp4[tid];              // 24*32 = 768 = blockDim ✓
    __syncthreads();
    float acc[24];
    #pragma unroll
    for (int r = 0; r < 24; ++r) acc[r] = 0.f;
    const float* wp = qkvw + (size_t)b*NC_H + tid;
    for (int d4 = 0; d4 < 32; ++d4) {
        float w0 = wp[(size_t)(4*d4)*768];
        float w1 = wp[(size_t)(4*d4+1)*768];
        float w2 = wp[(size_t)(4*d4+2)*768];
        float w3 = wp[(size_t)(4*d4+3)*768];
        #pragma unroll
        for (int r = 0; r < 24; ++r) {
            float4 xv = xs4[r*32 + d4];
            acc[r] = fmaf(xv.x, w0, fmaf(xv.y, w1, fmaf(xv.z, w2, fmaf(xv.w, w3, acc[r]))));
        }
    }
    int which = tid >> 8;
    int e = tid & 255;
    int hh = e >> 5, dh = e & 31;
    float* outp = (which == 0 ? q : (which == 1 ? k : v));
    outp += ((size_t)(b*HEADS + hh)*N + t0)*DH + dh;
    #pragma unroll
    for (int r = 0; r < 24; ++r) outp[r*DH] = acc[r];
}

// flash attention, lane = q-row.  2 waves/block split keys (interleaved 64-key
// chunks).  K/V rows wave-uniform (broadcast loads).  Mask staged per-wave in
// LDS (stride-65 -> 2-way = free).  Per-lane online softmax, no cross-lane ops
// in main loop; single LDS merge at the end.  Mask applied post-softmax.
__global__ __launch_bounds__(128) void k_attn2(const float* __restrict__ q,
                                               const float* __restrict__ k,
                                               const float* __restrict__ v,
                                               const float* __restrict__ mask,
                                               float* __restrict__ ao)
{
    __shared__ float mlds[2][64][65];   // 33.3 KB; merge buffer aliases this
    int bid = blockIdx.x;
    int h  = bid / 160;                 // same-mask blocks ≡ same bid mod 8 → same XCD
    int t  = bid % 160;
    int b  = t / 10;
    int qt = t % 10;
    int tid = threadIdx.x;
    int wave = tid >> 6, lane = tid & 63;
    int row0 = qt*64;
    int nrows = min(64, N - row0);      // 64 or 24
    int row = row0 + min(lane, nrows - 1);
    size_t bh = (size_t)(b*HEADS + h)*N;
    const float* Kb = k + bh*DH;
    const float* Vb = v + bh*DH;

    float qr[DH];
    {
        const float4* qp = (const float4*)(q + (bh + row)*DH);
        #pragma unroll
        for (int j = 0; j < 8; ++j) {
            float4 tq = qp[j];
            qr[4*j] = tq.x; qr[4*j+1] = tq.y; qr[4*j+2] = tq.z; qr[4*j+3] = tq.w;
        }
    }
    const float* mrow = mask + ((size_t)b*N + row)*N;
    const float scale = 0.17677669529663687f;   // 32^-0.5

    float M = -1e30f, S = 0.f;
    float acc[DH];
    #pragma unroll
    for (int d = 0; d < DH; ++d) acc[d] = 0.f;

    for (int c = wave; c < 10; c += 2) {
        int k0 = c*64;
        int nk = min(64, N - k0);       // 64, or 24 for chunk 9 (600-576)
        {   // stage mask chunk — private per-wave region, no barrier needed
            const float4* mp4 = (const float4*)(mrow + k0);
            int nj = nk >> 2;           // 16 or 6 (24/4) — exact, no tail
            for (int j = 0; j < nj; ++j) {
                float4 tm = mp4[j];
                mlds[wave][lane][4*j]   = tm.x;
                mlds[wave][lane][4*j+1] = tm.y;
                mlds[wave][lane][4*j+2] = tm.z;
                mlds[wave][lane][4*j+3] = tm.w;
            }
        }
        #pragma unroll 2
        for (int kk = 0; kk < nk; ++kk) {
            const float4* kp = (const float4*)(Kb + (size_t)(k0 + kk)*DH);
            float d0 = 0.f, d1 = 0.f, d2 = 0.f, d3 = 0.f;
            #pragma unroll
            for (int j = 0; j < 8; ++j) {
                float4 kd = kp[j];
                d0 = fmaf(kd.x, qr[4*j],   d0);
                d1 = fmaf(kd.y, qr[4*j+1], d1);
                d2 = fmaf(kd.z, qr[4*j+2], d2);
                d3 = fmaf(kd.w, qr[4*j+3], d3);
            }
            float dot = ((d0 + d1) + (d2 + d3)) * scale;
            if (__any(dot > M + 8.f)) {     // defer-max: rare after warm-up
                float Mn = fmaxf(M, dot);
                float sc = __expf(M - Mn);
                S *= sc;
                #pragma unroll
                for (int d = 0; d < DH; ++d) acc[d] *= sc;
                M = Mn;
            }
            float e = __expf(dot - M);
            S += e;                          // denominator WITHOUT mask
            float wgt = e * mlds[wave][lane][kk];   // numerator WITH mask
            const float4* vp = (const float4*)(Vb + (size_t)(k0 + kk)*DH);
            #pragma unroll
            for (int j = 0; j < 8; ++j) {
                float4 vd = vp[j];
                acc[4*j]   = fmaf(wgt, vd.x, acc[4*j]);
                acc[4*j+1] = fmaf(wgt, vd.y, acc[4*j+1]);
                acc[4*j+2] = fmaf(wgt, vd.z, acc[4*j+2]);
                acc[4*j+3] = fmaf(wgt, vd.w, acc[4*j+3]);
            }
        }
    }

    __syncthreads();                     // both waves done with mask LDS
    float* mb = (float*)mlds;            // reuse as [128][36] records
    float* rec = mb + (size_t)(wave*64 + lane)*36;
    #pragma unroll
    for (int j = 0; j < 8; ++j)
        ((float4*)rec)[j] = make_float4(acc[4*j], acc[4*j+1], acc[4*j+2], acc[4*j+3]);
    rec[32] = M; rec[33] = S;
    __syncthreads();
    if (wave == 0 && lane < nrows) {
        const float* r0 = mb + (size_t)lane*36;
        const float* r1 = mb + (size_t)(64 + lane)*36;
        float M0 = r0[32], S0 = r0[33], M1 = r1[32], S1 = r1[33];
        float Mn = fmaxf(M0, M1);
        float e0 = __expf(M0 - Mn), e1 = __expf(M1 - Mn);
        float inv = 1.f / (S0*e0 + S1*e1);
        float* o = ao + ((size_t)b*N + row)*INNER + h*DH;
        #pragma unroll
        for (int j = 0; j < 8; ++j) {
            float4 a0 = ((const float4*)r0)[j];
            float4 a1 = ((const float4*)r1)[j];
            float4 ov;
            ov.x = (a0.x*e0 + a1.x*e1)*inv;
            ov.y = (a0.y*e0 + a1.y*e1)*inv;
            ov.z = (a0.z*e0 + a1.z*e1)*inv;
            ov.w = (a0.w*e0 + a1.w*e1)*inv;
            ((float4*)o)[j] = ov;
        }
    }
}

__global__ __launch_bounds__(128) void k_final(const float* __restrict__ ao,
                                               const float* __restrict__ ow,
                                               float* __restrict__ out)
{
    __shared__ float4 os4[12*64];
    int b = blockIdx.x / 50, t0 = (blockIdx.x % 50)*12;
    int tid = threadIdx.x;
    const float4* ap4 = (const float4*)(ao + ((size_t)b*N + t0)*INNER);
    for (int i = tid; i < 12*64; i += 128) os4[i] = ap4[i];
    __syncthreads();
    float acc[12];
    #pragma unroll
    for (int r = 0; r < 12; ++r) acc[r] = 0.f;
    const float* wp = ow + (size_t)b*NC_O + tid;
    for (int i4 = 0; i4 < 64; ++i4) {
        float w0 = wp[(size_t)(4*i4)*DIM];
        float w1 = wp[(size_t)(4*i4+1)*DIM];
        float w2 = wp[(size_t)(4*i4+2)*DIM];
        float w3 = wp[(size_t)(4*i4+3)*DIM];
        #pragma unroll
        for (int r = 0; r < 12; ++r) {
            float4 av = os4[r*64 + i4];
            acc[r] = fmaf(av.x, w0, fmaf(av.y, w1, fmaf(av.z, w2, fmaf(av.w, w3, acc[r]))));
        }
    }
    float* op = out + ((size_t)b*N + t0)*DIM + tid;
    #pragma unroll
    for (int r = 0; r < 12; ++r) op[r*DIM] = acc[r];
}

extern "C" void kernel_launch(void* const* d_in, const int* in_sizes, int n_in,
                              void* d_out, int out_size, void* d_ws, size_t ws_size,
                              hipStream_t stream)
{
    const float* x          = (const float*)d_in[0];
    const float* mask       = (const float*)d_in[1];
    const float* resolution = (const float*)d_in[2];
    const float* framerate  = (const float*)d_in[3];
    const float* W1 = (const float*)d_in[4];
    const float* b1 = (const float*)d_in[5];
    const float* W2 = (const float*)d_in[6];
    const float* b2 = (const float*)d_in[7];
    const float* W3 = (const float*)d_in[8];
    const float* b3 = (const float*)d_in[9];
    const float* V1 = (const float*)d_in[10];
    const float* c1 = (const float*)d_in[11];
    const float* V2 = (const float*)d_in[12];
    const float* c2 = (const float*)d_in[13];
    const float* V3 = (const float*)d_in[14];
    const float* c3 = (const float*)d_in[15];

    float* ws = (float*)d_ws;
    float* t2 = ws;
    float* s2 = ws + 6144;
    float* h  = ws + 10240;
    float* ow = ws + 1583104;
    float* q  = ws + 2107392;
    float* k  = ws + 4564992;
    float* v  = ws + 7022592;
    float* ao = ws + 9480192;
    float* t1 = ws + 11937792;
    float* s1 = ws + 11943936;
    float* out = (float*)d_out;

    hipLaunchKernelGGL(k_chain1, dim3(1), dim3(384), 0, stream,
                       resolution, framerate, W1, b1, V1, c1, t1, s1);
    hipLaunchKernelGGL(k_chain2, dim3(40), dim3(256), 0, stream,
                       t1, s1, W2, b2, V2, c2, t2, s2);
    hipLaunchKernelGGL((k_hyper<D3, NC_H>), dim3(NC_H/256), dim3(256), 0, stream,
                       t2, W3, b3, h);
    hipLaunchKernelGGL((k_hyper<INNER, NC_O>), dim3(NC_O/256), dim3(256), 0, stream,
                       s2, V3, c3, ow);
    hipLaunchKernelGGL((k_softmax2<DIM, 3*INNER, 64, 4>), dim3(B*12), dim3(256), 0, stream, h);
    hipLaunchKernelGGL((k_softmax2<INNER, DIM, 32, 8>), dim3(B*4), dim3(256), 0, stream, ow);
    hipLaunchKernelGGL(k_proj, dim3(B*25), dim3(768), 0, stream, x, h, q, k, v);
    hipLaunchKernelGGL(k_attn2, dim3(B*HEADS*10), dim3(128), 0, stream, q, k, v, mask, ao);
    hipLaunchKernelGGL(k_final, dim3(B*50), dim3(128), 0, stream, ao, ow, out);
}

// Round 4
// 486.127 us; speedup vs baseline: 2.3103x; 1.9296x over previous
//
#include <hip/hip_runtime.h>
#include <hip/hip_bf16.h>
#include <math.h>

#define B 16
#define N 600
#define DIM 128
#define HEADS 8
#define DH 32
#define INNER 256
#define D3 384
#define NC_H (D3*INNER)   /* 98304 */
#define NC_O (INNER*DIM)  /* 32768 */

typedef _Float16 f16x8 __attribute__((ext_vector_type(8)));
typedef float    f32x4 __attribute__((ext_vector_type(4)));

// ---------------- ws layout (float offsets) ----------------
// t2 : 0        s2 : 6144     h : 10240     ow : 1583104
// t1 : 2107392  s1 : 2113536
// ao : 2117632  (2,457,600 f32)            [16][600][256]
// qh : 4575232  (2,457,600 halves)         [16][8][600][32] fp16, pre-scaled
// kh : 5804032  (2,457,600 halves)         [16][8][600][32] fp16
// vt : 7032832  (2,621,440 halves)         [16][8][32][640] fp16, transposed
// end: 8343552 f32 = 33.4 MB

__global__ void k_chain1(const float* __restrict__ resolution,
                         const float* __restrict__ framerate,
                         const float* __restrict__ W1, const float* __restrict__ b1,
                         const float* __restrict__ V1, const float* __restrict__ c1,
                         float* __restrict__ t1, float* __restrict__ s1)
{
    __shared__ float fr[B], re[B];
    int j = threadIdx.x;   // 384 threads
    if (j < B) { fr[j] = framerate[j]; re[j] = resolution[j]; }
    __syncthreads();
    {
        float w0 = W1[j], w1 = W1[D3 + j], bb = b1[j];
        for (int b = 0; b < B; ++b) t1[b*D3 + j] = fr[b]*w0 + re[b]*w1 + bb;
    }
    if (j < INNER) {
        float w0 = V1[j], w1 = V1[INNER + j], bb = c1[j];
        for (int b = 0; b < B; ++b) s1[b*INNER + j] = fr[b]*w0 + re[b]*w1 + bb;
    }
}

__global__ void k_chain2(const float* __restrict__ t1, const float* __restrict__ s1,
                         const float* __restrict__ W2, const float* __restrict__ b2,
                         const float* __restrict__ V2, const float* __restrict__ c2,
                         float* __restrict__ t2, float* __restrict__ s2)
{
    __shared__ float in_s[B*D3];
    int bid = blockIdx.x, tid = threadIdx.x;
    if (bid < 24) {
        for (int i = tid; i < B*D3; i += 256) in_s[i] = t1[i];
        __syncthreads();
        int flat = bid*256 + tid;
        int b = flat / D3, j = flat - b*D3;
        float acc = b2[j];
        #pragma unroll 4
        for (int kk = 0; kk < D3; ++kk)
            acc = fmaf(in_s[b*D3 + kk], W2[kk*D3 + j], acc);
        t2[flat] = acc;
    } else {
        for (int i = tid; i < B*INNER; i += 256) in_s[i] = s1[i];
        __syncthreads();
        int flat = (bid - 24)*256 + tid;
        int b = flat / INNER, j = flat - b*INNER;
        float acc = c2[j];
        #pragma unroll 4
        for (int kk = 0; kk < INNER; ++kk)
            acc = fmaf(in_s[b*INNER + kk], V2[kk*INNER + j], acc);
        s2[flat] = acc;
    }
}

template<int K, int NC>
__global__ void k_hyper(const float* __restrict__ tin, const float* __restrict__ W,
                        const float* __restrict__ bias, float* __restrict__ out)
{
    __shared__ float ts[B*K];
    int tid = threadIdx.x;
    for (int i = tid; i < B*K; i += 256) ts[i] = tin[i];
    __syncthreads();
    int col = blockIdx.x*256 + tid;
    float bb = bias[col];
    float acc[B];
    #pragma unroll
    for (int b = 0; b < B; ++b) acc[b] = bb;
    #pragma unroll 8
    for (int kk = 0; kk < K; ++kk) {
        float w = W[(size_t)kk*NC + col];
        #pragma unroll
        for (int b = 0; b < B; ++b) acc[b] = fmaf(ts[b*K + kk], w, acc[b]);
    }
    #pragma unroll
    for (int b = 0; b < B; ++b) out[(size_t)b*NC + col] = acc[b];
}

// softmax along R-axis of data[b][R][CPB]; COLS*GROUPS = 256 threads
template<int R, int CPB, int COLS, int GROUPS>
__global__ __launch_bounds__(256) void k_softmax2(float* __restrict__ data)
{
    constexpr int RPT = R / GROUPS;
    __shared__ float red[GROUPS][COLS];
    int tid = threadIdx.x;
    int col = tid % COLS, g = tid / COLS;
    int nb = CPB / COLS;
    int b = blockIdx.x / nb, cb = blockIdx.x % nb;
    float* p = data + (size_t)b*R*CPB + (size_t)g*RPT*CPB + cb*COLS + col;
    float vals[RPT];
    float m = -1e30f;
    #pragma unroll 4
    for (int r = 0; r < RPT; ++r) { vals[r] = p[(size_t)r*CPB]; m = fmaxf(m, vals[r]); }
    red[g][col] = m;
    __syncthreads();
    float M = red[0][col];
    #pragma unroll
    for (int gg = 1; gg < GROUPS; ++gg) M = fmaxf(M, red[gg][col]);
    __syncthreads();
    float s = 0.f;
    #pragma unroll 4
    for (int r = 0; r < RPT; ++r) { vals[r] = __expf(vals[r] - M); s += vals[r]; }
    red[g][col] = s;
    __syncthreads();
    float S = 0.f;
    #pragma unroll
    for (int gg = 0; gg < GROUPS; ++gg) S += red[gg][col];
    float inv = 1.f / S;
    #pragma unroll 4
    for (int r = 0; r < RPT; ++r) p[(size_t)r*CPB] = vals[r] * inv;
}

// x @ qkvw -> q,k (fp16 row-major, q pre-scaled) and v (fp16 transposed [d][n])
__global__ __launch_bounds__(768) void k_proj(const float* __restrict__ x,
                                              const float* __restrict__ qkvw,
                                              _Float16* __restrict__ qh,
                                              _Float16* __restrict__ kh,
                                              _Float16* __restrict__ vt)
{
    __shared__ float4 xs4[24*32];
    int b = blockIdx.x / 25, t0 = (blockIdx.x % 25)*24;
    int tid = threadIdx.x;
    const float4* xp4 = (const float4*)(x + ((size_t)b*N + t0)*DIM);
    xs4[tid] = xp4[tid];              // 24*32 = 768 = blockDim
    __syncthreads();
    float acc[24];
    #pragma unroll
    for (int r = 0; r < 24; ++r) acc[r] = 0.f;
    const float* wp = qkvw + (size_t)b*NC_H + tid;
    for (int d4 = 0; d4 < 32; ++d4) {
        float w0 = wp[(size_t)(4*d4)*768];
        float w1 = wp[(size_t)(4*d4+1)*768];
        float w2 = wp[(size_t)(4*d4+2)*768];
        float w3 = wp[(size_t)(4*d4+3)*768];
        #pragma unroll
        for (int r = 0; r < 24; ++r) {
            float4 xv = xs4[r*32 + d4];
            acc[r] = fmaf(xv.x, w0, fmaf(xv.y, w1, fmaf(xv.z, w2, fmaf(xv.w, w3, acc[r]))));
        }
    }
    int which = tid >> 8;
    int e = tid & 255;
    int hh = e >> 5, dh = e & 31;
    const float scale = 0.17677669529663687f;   // 32^-0.5 folded into Q
    if (which == 0) {
        _Float16* qp = qh + ((size_t)(b*HEADS + hh)*N + t0)*DH + dh;
        #pragma unroll
        for (int r = 0; r < 24; ++r) qp[r*DH] = (_Float16)(acc[r]*scale);
    } else if (which == 1) {
        _Float16* kp = kh + ((size_t)(b*HEADS + hh)*N + t0)*DH + dh;
        #pragma unroll
        for (int r = 0; r < 24; ++r) kp[r*DH] = (_Float16)acc[r];
    } else {
        _Float16* vp = vt + ((size_t)(b*HEADS + hh)*DH + dh)*640 + t0;
        #pragma unroll
        for (int r = 0; r < 24; ++r) vp[r] = (_Float16)acc[r];
    }
}

static __device__ inline unsigned pk2(float a, float b) {
    auto t = __builtin_amdgcn_cvt_pkrtz(a, b);   // __fp16 ext_vector(2)
    return __builtin_bit_cast(unsigned, t);
}

// MFMA flash attention. 1 wave/block, 32 q-rows (2 tiles), 64-key chunks.
// S^T = mfma(K, Q^T) and out^T = mfma(V^T, P^T): q = lane&15 everywhere ->
// softmax state fully lane-local. P^T bounced through 4.6KB LDS.
// Mask applied post-softmax (numerator only).
__global__ __launch_bounds__(64) void k_attn3(const _Float16* __restrict__ qh,
                                              const _Float16* __restrict__ kh,
                                              const _Float16* __restrict__ vt,
                                              const float* __restrict__ mask,
                                              float* __restrict__ ao)
{
    __shared__ __align__(16) _Float16 plds[2][16][72];
    int bid = blockIdx.x;
    int h = bid / 304, rem = bid % 304;       // h slow: 8 same-mask blocks share XCD class
    int b = rem / 19, qc = rem % 19;
    int lane = threadIdx.x;
    int ql = lane & 15, g = lane >> 4;
    int q0 = qc * 32;
    size_t bh = (size_t)(b*HEADS + h);
    const _Float16* Qb  = qh + bh*(size_t)(N*DH);
    const _Float16* Kb  = kh + bh*(size_t)(N*DH);
    const _Float16* Vtb = vt + bh*(size_t)(DH*640);

    f16x8 qf[2];
    const float* mrow[2];
    int qrow[2];
    #pragma unroll
    for (int qt = 0; qt < 2; ++qt) {
        qrow[qt] = q0 + qt*16 + ql;
        int r = qrow[qt] > 599 ? 599 : qrow[qt];
        qf[qt] = *(const f16x8*)(Qb + (size_t)r*DH + g*8);
        mrow[qt] = mask + ((size_t)b*N + r)*N;
    }

    float M[2] = {-1e30f, -1e30f}, S[2] = {0.f, 0.f};
    f32x4 acc[2][2];
    #pragma unroll
    for (int qt = 0; qt < 2; ++qt)
        #pragma unroll
        for (int dt = 0; dt < 2; ++dt)
            acc[qt][dt] = (f32x4){0.f, 0.f, 0.f, 0.f};

    for (int k0 = 0; k0 < N; k0 += 64) {
        // ---- QK^T: 4 key-subtiles x 2 q-tiles ----
        f32x4 st[2][4];
        #pragma unroll
        for (int t = 0; t < 4; ++t) {
            int kr = k0 + 16*t + ql; if (kr > 599) kr = 599;
            f16x8 kf = *(const f16x8*)(Kb + (size_t)kr*DH + g*8);
            #pragma unroll
            for (int qt = 0; qt < 2; ++qt)
                st[qt][t] = __builtin_amdgcn_mfma_f32_16x16x32_f16(
                    kf, qf[qt], (f32x4){0.f,0.f,0.f,0.f}, 0, 0, 0);
        }
        // ---- softmax (per q-tile, lane-local on q=ql) ----
        #pragma unroll
        for (int qt = 0; qt < 2; ++qt) {
            float tm = -1e30f;
            #pragma unroll
            for (int t = 0; t < 4; ++t) {
                #pragma unroll
                for (int r = 0; r < 4; ++r) {
                    int key = k0 + 16*t + 4*g + r;
                    float sv = st[qt][t][r];
                    if (key >= N) sv = -1e30f;
                    st[qt][t][r] = sv;
                    tm = fmaxf(tm, sv);
                }
            }
            tm = fmaxf(tm, __shfl_xor(tm, 16));
            tm = fmaxf(tm, __shfl_xor(tm, 32));
            float Mn = fmaxf(M[qt], tm);
            float scl = __expf(M[qt] - Mn);
            M[qt] = Mn;
            S[qt] *= scl;
            acc[qt][0] *= scl;
            acc[qt][1] *= scl;
            float ssum = 0.f;
            #pragma unroll
            for (int t = 0; t < 4; ++t) {
                int keyb = k0 + 16*t + 4*g;
                float e0 = __expf(st[qt][t][0] - Mn);
                float e1 = __expf(st[qt][t][1] - Mn);
                float e2 = __expf(st[qt][t][2] - Mn);
                float e3 = __expf(st[qt][t][3] - Mn);
                ssum += (e0 + e1) + (e2 + e3);
                int c0 = keyb   > 599 ? 599 : keyb;
                int c1 = keyb+1 > 599 ? 599 : keyb+1;
                int c2 = keyb+2 > 599 ? 599 : keyb+2;
                int c3 = keyb+3 > 599 ? 599 : keyb+3;
                float m0 = mrow[qt][c0], m1 = mrow[qt][c1];
                float m2 = mrow[qt][c2], m3 = mrow[qt][c3];
                *(unsigned*)&plds[qt][ql][16*t + 4*g]     = pk2(e0*m0, e1*m1);
                *(unsigned*)&plds[qt][ql][16*t + 4*g + 2] = pk2(e2*m2, e3*m3);
            }
            ssum += __shfl_xor(ssum, 16);
            ssum += __shfl_xor(ssum, 32);
            S[qt] += ssum;
        }
        // ---- PV: out^T += V^T-frag x P^T-frag ----
        #pragma unroll
        for (int win = 0; win < 2; ++win) {
            f16x8 pf[2];
            #pragma unroll
            for (int qt = 0; qt < 2; ++qt)
                pf[qt] = *(const f16x8*)&plds[qt][ql][win*32 + g*8];
            #pragma unroll
            for (int dt = 0; dt < 2; ++dt) {
                f16x8 vf = *(const f16x8*)(Vtb + (size_t)(dt*16 + ql)*640 + k0 + win*32 + g*8);
                #pragma unroll
                for (int qt = 0; qt < 2; ++qt)
                    acc[qt][dt] = __builtin_amdgcn_mfma_f32_16x16x32_f16(
                        vf, pf[qt], acc[qt][dt], 0, 0, 0);
            }
        }
    }

    // ---- epilogue: out[q][d] = acc^T[d][q] / S[q] ----
    #pragma unroll
    for (int qt = 0; qt < 2; ++qt) {
        if (qrow[qt] < N) {
            float inv = 1.f / S[qt];
            float* o = ao + ((size_t)b*N + qrow[qt])*INNER + h*DH;
            #pragma unroll
            for (int dt = 0; dt < 2; ++dt)
                #pragma unroll
                for (int r = 0; r < 4; ++r)
                    o[dt*16 + 4*g + r] = acc[qt][dt][r] * inv;
        }
    }
}

__global__ __launch_bounds__(128) void k_final(const float* __restrict__ ao,
                                               const float* __restrict__ ow,
                                               float* __restrict__ out)
{
    __shared__ float4 os4[12*64];
    int b = blockIdx.x / 50, t0 = (blockIdx.x % 50)*12;
    int tid = threadIdx.x;
    const float4* ap4 = (const float4*)(ao + ((size_t)b*N + t0)*INNER);
    for (int i = tid; i < 12*64; i += 128) os4[i] = ap4[i];
    __syncthreads();
    float acc[12];
    #pragma unroll
    for (int r = 0; r < 12; ++r) acc[r] = 0.f;
    const float* wp = ow + (size_t)b*NC_O + tid;
    for (int i4 = 0; i4 < 64; ++i4) {
        float w0 = wp[(size_t)(4*i4)*DIM];
        float w1 = wp[(size_t)(4*i4+1)*DIM];
        float w2 = wp[(size_t)(4*i4+2)*DIM];
        float w3 = wp[(size_t)(4*i4+3)*DIM];
        #pragma unroll
        for (int r = 0; r < 12; ++r) {
            float4 av = os4[r*64 + i4];
            acc[r] = fmaf(av.x, w0, fmaf(av.y, w1, fmaf(av.z, w2, fmaf(av.w, w3, acc[r]))));
        }
    }
    float* op = out + ((size_t)b*N + t0)*DIM + tid;
    #pragma unroll
    for (int r = 0; r < 12; ++r) op[r*DIM] = acc[r];
}

extern "C" void kernel_launch(void* const* d_in, const int* in_sizes, int n_in,
                              void* d_out, int out_size, void* d_ws, size_t ws_size,
                              hipStream_t stream)
{
    const float* x          = (const float*)d_in[0];
    const float* mask       = (const float*)d_in[1];
    const float* resolution = (const float*)d_in[2];
    const float* framerate  = (const float*)d_in[3];
    const float* W1 = (const float*)d_in[4];
    const float* b1 = (const float*)d_in[5];
    const float* W2 = (const float*)d_in[6];
    const float* b2 = (const float*)d_in[7];
    const float* W3 = (const float*)d_in[8];
    const float* b3 = (const float*)d_in[9];
    const float* V1 = (const float*)d_in[10];
    const float* c1 = (const float*)d_in[11];
    const float* V2 = (const float*)d_in[12];
    const float* c2 = (const float*)d_in[13];
    const float* V3 = (const float*)d_in[14];
    const float* c3 = (const float*)d_in[15];

    float* ws = (float*)d_ws;
    float* t2 = ws;
    float* s2 = ws + 6144;
    float* h  = ws + 10240;
    float* ow = ws + 1583104;
    float* t1 = ws + 2107392;
    float* s1 = ws + 2113536;
    float* ao = ws + 2117632;
    _Float16* qh = (_Float16*)(ws + 4575232);
    _Float16* kh = (_Float16*)(ws + 5804032);
    _Float16* vt = (_Float16*)(ws + 7032832);
    float* out = (float*)d_out;

    hipLaunchKernelGGL(k_chain1, dim3(1), dim3(384), 0, stream,
                       resolution, framerate, W1, b1, V1, c1, t1, s1);
    hipLaunchKernelGGL(k_chain2, dim3(40), dim3(256), 0, stream,
                       t1, s1, W2, b2, V2, c2, t2, s2);
    hipLaunchKernelGGL((k_hyper<D3, NC_H>), dim3(NC_H/256), dim3(256), 0, stream,
                       t2, W3, b3, h);
    hipLaunchKernelGGL((k_hyper<INNER, NC_O>), dim3(NC_O/256), dim3(256), 0, stream,
                       s2, V3, c3, ow);
    hipLaunchKernelGGL((k_softmax2<DIM, 3*INNER, 64, 4>), dim3(B*12), dim3(256), 0, stream, h);
    hipLaunchKernelGGL((k_softmax2<INNER, DIM, 32, 8>), dim3(B*4), dim3(256), 0, stream, ow);
    hipLaunchKernelGGL(k_proj, dim3(B*25), dim3(768), 0, stream, x, h, qh, kh, vt);
    hipLaunchKernelGGL(k_attn3, dim3(8*304), dim3(64), 0, stream, qh, kh, vt, mask, ao);
    hipLaunchKernelGGL(k_final, dim3(B*50), dim3(128), 0, stream, ao, ow, out);
}

// Round 6
// 371.670 us; speedup vs baseline: 3.0217x; 1.3080x over previous
//
#include <hip/hip_runtime.h>
#include <hip/hip_bf16.h>
#include <math.h>

#define B 16
#define N 600
#define DIM 128
#define HEADS 8
#define DH 32
#define INNER 256
#define D3 384
#define NC_H (D3*INNER)   /* 98304 */
#define NC_O (INNER*DIM)  /* 32768 */

typedef _Float16 f16x8 __attribute__((ext_vector_type(8)));
typedef float    f32x4 __attribute__((ext_vector_type(4)));

// ---------------- ws layout (float offsets) ----------------
// t2 : 0        s2 : 6144     h : 10240 (1,572,864)   ow : 1583104 (524,288)
// t1 : 2107392  s1 : 2113536
// ao : 2117632  (2,457,600 f32)            [16][600][256]
// qh : 4575232  (2,457,600 halves)         [16][8][600][32] fp16, pre-scaled
// kh : 5804032  (2,457,600 halves)         [16][8][600][32] fp16
// vt : 7032832  (2,621,440 halves)         [16][8][32][640] fp16, transposed
//      cols 600..639 zero-filled by k_proj tail tiles (pO aliases this region;
//      f32 leftovers reinterpreted as fp16 can be NaN -> 0*NaN = NaN in MFMA)
// end: 8343552 f32 = 33.4 MB
// pH : aliases 2117632 .. 6836224  (3 x 1,572,864)  — consumed before qh/kh/vt written
// pO : aliases 6836224 .. 7884800  (2 x 524,288)

__global__ void k_chain1(const float* __restrict__ resolution,
                         const float* __restrict__ framerate,
                         const float* __restrict__ W1, const float* __restrict__ b1,
                         const float* __restrict__ V1, const float* __restrict__ c1,
                         float* __restrict__ t1, float* __restrict__ s1)
{
    __shared__ float fr[B], re[B];
    int j = threadIdx.x;   // 384 threads
    if (j < B) { fr[j] = framerate[j]; re[j] = resolution[j]; }
    __syncthreads();
    {
        float w0 = W1[j], w1 = W1[D3 + j], bb = b1[j];
        for (int b = 0; b < B; ++b) t1[b*D3 + j] = fr[b]*w0 + re[b]*w1 + bb;
    }
    if (j < INNER) {
        float w0 = V1[j], w1 = V1[INNER + j], bb = c1[j];
        for (int b = 0; b < B; ++b) s1[b*INNER + j] = fr[b]*w0 + re[b]*w1 + bb;
    }
}

__global__ void k_chain2(const float* __restrict__ t1, const float* __restrict__ s1,
                         const float* __restrict__ W2, const float* __restrict__ b2,
                         const float* __restrict__ V2, const float* __restrict__ c2,
                         float* __restrict__ t2, float* __restrict__ s2)
{
    __shared__ float in_s[B*D3];
    int bid = blockIdx.x, tid = threadIdx.x;
    if (bid < 24) {
        for (int i = tid; i < B*D3; i += 256) in_s[i] = t1[i];
        __syncthreads();
        int flat = bid*256 + tid;
        int b = flat / D3, j = flat - b*D3;
        float acc = b2[j];
        #pragma unroll 4
        for (int kk = 0; kk < D3; ++kk)
            acc = fmaf(in_s[b*D3 + kk], W2[kk*D3 + j], acc);
        t2[flat] = acc;
    } else {
        for (int i = tid; i < B*INNER; i += 256) in_s[i] = s1[i];
        __syncthreads();
        int flat = (bid - 24)*256 + tid;
        int b = flat / INNER, j = flat - b*INNER;
        float acc = c2[j];
        #pragma unroll 4
        for (int kk = 0; kk < INNER; ++kk)
            acc = fmaf(in_s[b*INNER + kk], V2[kk*INNER + j], acc);
        s2[flat] = acc;
    }
}

// Split-K hypernet GEMM: grid = (NC/256) x KSG, 512 threads = 2 K-halves.
// partial[ksg][b][col] written by half 0 after LDS merge.
template<int K, int NC, int KSG>
__global__ __launch_bounds__(512) void k_hyper2(const float* __restrict__ tin,
                                                const float* __restrict__ W,
                                                float* __restrict__ partial)
{
    constexpr int KR = K / KSG;      // K-range per block
    constexpr int KH = KR / 2;       // per half-block
    __shared__ float ts[B*KR];
    __shared__ float mrg[B*256];
    int tid = threadIdx.x;
    int cb = blockIdx.x % (NC/256), ksg = blockIdx.x / (NC/256);
    int half = tid >> 8, c = tid & 255;
    int col = cb*256 + c;
    for (int i = tid; i < B*KR; i += 512) {
        int b = i / KR, kk = i - b*KR;
        ts[i] = tin[b*K + ksg*KR + kk];
    }
    __syncthreads();
    float acc[B];
    #pragma unroll
    for (int b = 0; b < B; ++b) acc[b] = 0.f;
    const float* wp = W + (size_t)(ksg*KR + half*KH)*NC + col;
    const int tbase = half*KH;
    #pragma unroll 8
    for (int kk = 0; kk < KH; ++kk) {
        float w = wp[(size_t)kk*NC];
        #pragma unroll
        for (int b = 0; b < B; ++b) acc[b] = fmaf(ts[b*KR + tbase + kk], w, acc[b]);
    }
    if (half) {
        #pragma unroll
        for (int b = 0; b < B; ++b) mrg[b*256 + c] = acc[b];
    }
    __syncthreads();
    if (!half) {
        float* pp = partial + (size_t)ksg*B*NC + col;
        #pragma unroll
        for (int b = 0; b < B; ++b) pp[(size_t)b*NC] = acc[b] + mrg[b*256 + c];
    }
}

template<int NC, int KSG>
__global__ __launch_bounds__(256) void k_reduce(const float* __restrict__ partial,
                                                const float* __restrict__ bias,
                                                float* __restrict__ out)
{
    int i = blockIdx.x*256 + threadIdx.x;   // i in [0, B*NC)
    int col = i % NC;
    float s = bias[col];
    #pragma unroll
    for (int ks = 0; ks < KSG; ++ks) s += partial[(size_t)ks*B*NC + i];
    out[i] = s;
}

// softmax along R-axis of data[b][R][CPB]; COLS*GROUPS = 256 threads
template<int R, int CPB, int COLS, int GROUPS>
__global__ __launch_bounds__(256) void k_softmax2(float* __restrict__ data)
{
    constexpr int RPT = R / GROUPS;
    __shared__ float red[GROUPS][COLS];
    int tid = threadIdx.x;
    int col = tid % COLS, g = tid / COLS;
    int nb = CPB / COLS;
    int b = blockIdx.x / nb, cb = blockIdx.x % nb;
    float* p = data + (size_t)b*R*CPB + (size_t)g*RPT*CPB + cb*COLS + col;
    float vals[RPT];
    float m = -1e30f;
    #pragma unroll 4
    for (int r = 0; r < RPT; ++r) { vals[r] = p[(size_t)r*CPB]; m = fmaxf(m, vals[r]); }
    red[g][col] = m;
    __syncthreads();
    float M = red[0][col];
    #pragma unroll
    for (int gg = 1; gg < GROUPS; ++gg) M = fmaxf(M, red[gg][col]);
    __syncthreads();
    float s = 0.f;
    #pragma unroll 4
    for (int r = 0; r < RPT; ++r) { vals[r] = __expf(vals[r] - M); s += vals[r]; }
    red[g][col] = s;
    __syncthreads();
    float S = 0.f;
    #pragma unroll
    for (int gg = 0; gg < GROUPS; ++gg) S += red[gg][col];
    float inv = 1.f / S;
    #pragma unroll 4
    for (int r = 0; r < RPT; ++r) p[(size_t)r*CPB] = vals[r] * inv;
}

// x @ qkvw -> q,k (fp16 row-major, q pre-scaled) and v (fp16 transposed [d][n])
__global__ __launch_bounds__(768) void k_proj(const float* __restrict__ x,
                                              const float* __restrict__ qkvw,
                                              _Float16* __restrict__ qh,
                                              _Float16* __restrict__ kh,
                                              _Float16* __restrict__ vt)
{
    __shared__ float4 xs4[24*32];
    int b = blockIdx.x / 25, t0 = (blockIdx.x % 25)*24;
    int tid = threadIdx.x;
    const float4* xp4 = (const float4*)(x + ((size_t)b*N + t0)*DIM);
    xs4[tid] = xp4[tid];              // 24*32 = 768 = blockDim
    __syncthreads();
    float acc[24];
    #pragma unroll
    for (int r = 0; r < 24; ++r) acc[r] = 0.f;
    const float* wp = qkvw + (size_t)b*NC_H + tid;
    for (int d4 = 0; d4 < 32; ++d4) {
        float w0 = wp[(size_t)(4*d4)*768];
        float w1 = wp[(size_t)(4*d4+1)*768];
        float w2 = wp[(size_t)(4*d4+2)*768];
        float w3 = wp[(size_t)(4*d4+3)*768];
        #pragma unroll
        for (int r = 0; r < 24; ++r) {
            float4 xv = xs4[r*32 + d4];
            acc[r] = fmaf(xv.x, w0, fmaf(xv.y, w1, fmaf(xv.z, w2, fmaf(xv.w, w3, acc[r]))));
        }
    }
    int which = tid >> 8;
    int e = tid & 255;
    int hh = e >> 5, dh = e & 31;
    const float scale = 0.17677669529663687f;   // 32^-0.5 folded into Q
    if (which == 0) {
        _Float16* qp = qh + ((size_t)(b*HEADS + hh)*N + t0)*DH + dh;
        #pragma unroll
        for (int r = 0; r < 24; ++r) qp[r*DH] = (_Float16)(acc[r]*scale);
    } else if (which == 1) {
        _Float16* kp = kh + ((size_t)(b*HEADS + hh)*N + t0)*DH + dh;
        #pragma unroll
        for (int r = 0; r < 24; ++r) kp[r*DH] = (_Float16)acc[r];
    } else {
        _Float16* vp = vt + ((size_t)(b*HEADS + hh)*DH + dh)*640 + t0;
        #pragma unroll
        for (int r = 0; r < 24; ++r) vp[r] = (_Float16)acc[r];
        if (t0 == 576) {
            // zero-fill cols 600..639: pO aliasing leaves f32 garbage here whose
            // fp16 reinterpretation can be NaN; PV does 0*NaN = NaN otherwise.
            #pragma unroll
            for (int r = 24; r < 64; ++r) vp[r] = (_Float16)0.f;
        }
    }
}

static __device__ inline unsigned pk2(float a, float b) {
    auto t = __builtin_amdgcn_cvt_pkrtz(a, b);   // __fp16 ext_vector(2)
    return __builtin_bit_cast(unsigned, t);
}

// MFMA flash attention. 1 wave/block, 32 q-rows (2 tiles), 64-key chunks.
// S^T = mfma(K, Q^T) and out^T = mfma(V^T, P^T): q = lane&15 everywhere ->
// softmax state fully lane-local. P^T bounced through 4.6KB LDS.
// Mask applied post-softmax (numerator only).
__global__ __launch_bounds__(64) void k_attn3(const _Float16* __restrict__ qh,
                                              const _Float16* __restrict__ kh,
                                              const _Float16* __restrict__ vt,
                                              const float* __restrict__ mask,
                                              float* __restrict__ ao)
{
    __shared__ __align__(16) _Float16 plds[2][16][72];
    int bid = blockIdx.x;
    int h = bid / 304, rem = bid % 304;       // h slow: 8 same-mask blocks share XCD class
    int b = rem / 19, qc = rem % 19;
    int lane = threadIdx.x;
    int ql = lane & 15, g = lane >> 4;
    int q0 = qc * 32;
    size_t bh = (size_t)(b*HEADS + h);
    const _Float16* Qb  = qh + bh*(size_t)(N*DH);
    const _Float16* Kb  = kh + bh*(size_t)(N*DH);
    const _Float16* Vtb = vt + bh*(size_t)(DH*640);

    f16x8 qf[2];
    const float* mrow[2];
    int qrow[2];
    #pragma unroll
    for (int qt = 0; qt < 2; ++qt) {
        qrow[qt] = q0 + qt*16 + ql;
        int r = qrow[qt] > 599 ? 599 : qrow[qt];
        qf[qt] = *(const f16x8*)(Qb + (size_t)r*DH + g*8);
        mrow[qt] = mask + ((size_t)b*N + r)*N;
    }

    float M[2] = {-1e30f, -1e30f}, S[2] = {0.f, 0.f};
    f32x4 acc[2][2];
    #pragma unroll
    for (int qt = 0; qt < 2; ++qt)
        #pragma unroll
        for (int dt = 0; dt < 2; ++dt)
            acc[qt][dt] = (f32x4){0.f, 0.f, 0.f, 0.f};

    for (int k0 = 0; k0 < N; k0 += 64) {
        // ---- QK^T: 4 key-subtiles x 2 q-tiles ----
        f32x4 st[2][4];
        #pragma unroll
        for (int t = 0; t < 4; ++t) {
            int kr = k0 + 16*t + ql; if (kr > 599) kr = 599;
            f16x8 kf = *(const f16x8*)(Kb + (size_t)kr*DH + g*8);
            #pragma unroll
            for (int qt = 0; qt < 2; ++qt)
                st[qt][t] = __builtin_amdgcn_mfma_f32_16x16x32_f16(
                    kf, qf[qt], (f32x4){0.f,0.f,0.f,0.f}, 0, 0, 0);
        }
        // ---- softmax (per q-tile, lane-local on q=ql) ----
        #pragma unroll
        for (int qt = 0; qt < 2; ++qt) {
            float tm = -1e30f;
            #pragma unroll
            for (int t = 0; t < 4; ++t) {
                #pragma unroll
                for (int r = 0; r < 4; ++r) {
                    int key = k0 + 16*t + 4*g + r;
                    float sv = st[qt][t][r];
                    if (key >= N) sv = -1e30f;
                    st[qt][t][r] = sv;
                    tm = fmaxf(tm, sv);
                }
            }
            tm = fmaxf(tm, __shfl_xor(tm, 16));
            tm = fmaxf(tm, __shfl_xor(tm, 32));
            float Mn = fmaxf(M[qt], tm);
            float scl = __expf(M[qt] - Mn);
            M[qt] = Mn;
            S[qt] *= scl;
            acc[qt][0] *= scl;
            acc[qt][1] *= scl;
            float ssum = 0.f;
            #pragma unroll
            for (int t = 0; t < 4; ++t) {
                int keyb = k0 + 16*t + 4*g;
                float e0 = __expf(st[qt][t][0] - Mn);
                float e1 = __expf(st[qt][t][1] - Mn);
                float e2 = __expf(st[qt][t][2] - Mn);
                float e3 = __expf(st[qt][t][3] - Mn);
                ssum += (e0 + e1) + (e2 + e3);
                int c0 = keyb   > 599 ? 599 : keyb;
                int c1 = keyb+1 > 599 ? 599 : keyb+1;
                int c2 = keyb+2 > 599 ? 599 : keyb+2;
                int c3 = keyb+3 > 599 ? 599 : keyb+3;
                float m0 = mrow[qt][c0], m1 = mrow[qt][c1];
                float m2 = mrow[qt][c2], m3 = mrow[qt][c3];
                *(unsigned*)&plds[qt][ql][16*t + 4*g]     = pk2(e0*m0, e1*m1);
                *(unsigned*)&plds[qt][ql][16*t + 4*g + 2] = pk2(e2*m2, e3*m3);
            }
            ssum += __shfl_xor(ssum, 16);
            ssum += __shfl_xor(ssum, 32);
            S[qt] += ssum;
        }
        // ---- PV: out^T += V^T-frag x P^T-frag ----
        #pragma unroll
        for (int win = 0; win < 2; ++win) {
            f16x8 pf[2];
            #pragma unroll
            for (int qt = 0; qt < 2; ++qt)
                pf[qt] = *(const f16x8*)&plds[qt][ql][win*32 + g*8];
            #pragma unroll
            for (int dt = 0; dt < 2; ++dt) {
                f16x8 vf = *(const f16x8*)(Vtb + (size_t)(dt*16 + ql)*640 + k0 + win*32 + g*8);
                #pragma unroll
                for (int qt = 0; qt < 2; ++qt)
                    acc[qt][dt] = __builtin_amdgcn_mfma_f32_16x16x32_f16(
                        vf, pf[qt], acc[qt][dt], 0, 0, 0);
            }
        }
    }

    // ---- epilogue: out[q][d] = acc^T[d][q] / S[q] ----
    #pragma unroll
    for (int qt = 0; qt < 2; ++qt) {
        if (qrow[qt] < N) {
            float inv = 1.f / S[qt];
            float* o = ao + ((size_t)b*N + qrow[qt])*INNER + h*DH;
            #pragma unroll
            for (int dt = 0; dt < 2; ++dt)
                #pragma unroll
                for (int r = 0; r < 4; ++r)
                    o[dt*16 + 4*g + r] = acc[qt][dt][r] * inv;
        }
    }
}

__global__ __launch_bounds__(128) void k_final(const float* __restrict__ ao,
                                               const float* __restrict__ ow,
                                               float* __restrict__ out)
{
    __shared__ float4 os4[12*64];
    int b = blockIdx.x / 50, t0 = (blockIdx.x % 50)*12;
    int tid = threadIdx.x;
    const float4* ap4 = (const float4*)(ao + ((size_t)b*N + t0)*INNER);
    for (int i = tid; i < 12*64; i += 128) os4[i] = ap4[i];
    __syncthreads();
    float acc[12];
    #pragma unroll
    for (int r = 0; r < 12; ++r) acc[r] = 0.f;
    const float* wp = ow + (size_t)b*NC_O + tid;
    for (int i4 = 0; i4 < 64; ++i4) {
        float w0 = wp[(size_t)(4*i4)*DIM];
        float w1 = wp[(size_t)(4*i4+1)*DIM];
        float w2 = wp[(size_t)(4*i4+2)*DIM];
        float w3 = wp[(size_t)(4*i4+3)*DIM];
        #pragma unroll
        for (int r = 0; r < 12; ++r) {
            float4 av = os4[r*64 + i4];
            acc[r] = fmaf(av.x, w0, fmaf(av.y, w1, fmaf(av.z, w2, fmaf(av.w, w3, acc[r]))));
        }
    }
    float* op = out + ((size_t)b*N + t0)*DIM + tid;
    #pragma unroll
    for (int r = 0; r < 12; ++r) op[r*DIM] = acc[r];
}

extern "C" void kernel_launch(void* const* d_in, const int* in_sizes, int n_in,
                              void* d_out, int out_size, void* d_ws, size_t ws_size,
                              hipStream_t stream)
{
    const float* x          = (const float*)d_in[0];
    const float* mask       = (const float*)d_in[1];
    const float* resolution = (const float*)d_in[2];
    const float* framerate  = (const float*)d_in[3];
    const float* W1 = (const float*)d_in[4];
    const float* b1 = (const float*)d_in[5];
    const float* W2 = (const float*)d_in[6];
    const float* b2 = (const float*)d_in[7];
    const float* W3 = (const float*)d_in[8];
    const float* b3 = (const float*)d_in[9];
    const float* V1 = (const float*)d_in[10];
    const float* c1 = (const float*)d_in[11];
    const float* V2 = (const float*)d_in[12];
    const float* c2 = (const float*)d_in[13];
    const float* V3 = (const float*)d_in[14];
    const float* c3 = (const float*)d_in[15];

    float* ws = (float*)d_ws;
    float* t2 = ws;
    float* s2 = ws + 6144;
    float* h  = ws + 10240;
    float* ow = ws + 1583104;
    float* t1 = ws + 2107392;
    float* s1 = ws + 2113536;
    float* ao = ws + 2117632;
    float* pH = ws + 2117632;               // 3 x 1,572,864 (aliases ao/qh)
    float* pO = ws + 6836224;               // 2 x 524,288   (aliases kh/vt)
    _Float16* qh = (_Float16*)(ws + 4575232);
    _Float16* kh = (_Float16*)(ws + 5804032);
    _Float16* vt = (_Float16*)(ws + 7032832);
    float* out = (float*)d_out;

    hipLaunchKernelGGL(k_chain1, dim3(1), dim3(384), 0, stream,
                       resolution, framerate, W1, b1, V1, c1, t1, s1);
    hipLaunchKernelGGL(k_chain2, dim3(40), dim3(256), 0, stream,
                       t1, s1, W2, b2, V2, c2, t2, s2);
    hipLaunchKernelGGL((k_hyper2<D3, NC_H, 3>), dim3((NC_H/256)*3), dim3(512), 0, stream,
                       t2, W3, pH);
    hipLaunchKernelGGL((k_hyper2<INNER, NC_O, 2>), dim3((NC_O/256)*2), dim3(512), 0, stream,
                       s2, V3, pO);
    hipLaunchKernelGGL((k_reduce<NC_H, 3>), dim3(B*NC_H/256), dim3(256), 0, stream,
                       pH, b3, h);
    hipLaunchKernelGGL((k_reduce<NC_O, 2>), dim3(B*NC_O/256), dim3(256), 0, stream,
                       pO, c3, ow);
    hipLaunchKernelGGL((k_softmax2<DIM, 3*INNER, 64, 4>), dim3(B*12), dim3(256), 0, stream, h);
    hipLaunchKernelGGL((k_softmax2<INNER, DIM, 32, 8>), dim3(B*4), dim3(256), 0, stream, ow);
    hipLaunchKernelGGL(k_proj, dim3(B*25), dim3(768), 0, stream, x, h, qh, kh, vt);
    hipLaunchKernelGGL(k_attn3, dim3(8*304), dim3(64), 0, stream, qh, kh, vt, mask, ao);
    hipLaunchKernelGGL(k_final, dim3(B*50), dim3(128), 0, stream, ao, ow, out);
}

// Round 7
// 287.608 us; speedup vs baseline: 3.9049x; 1.2923x over previous
//
#include <hip/hip_runtime.h>
#include <hip/hip_bf16.h>
#include <math.h>

#define B 16
#define N 600
#define DIM 128
#define HEADS 8
#define DH 32
#define INNER 256
#define D3 384
#define NC_H (D3*INNER)   /* 98304 */
#define NC_O (INNER*DIM)  /* 32768 */

typedef _Float16 f16x8 __attribute__((ext_vector_type(8)));
typedef float    f32x4 __attribute__((ext_vector_type(4)));

// ---------------- ws layout (float offsets) ----------------
// t2 : 0        s2 : 6144     h : 10240 (1,572,864)   ow : 1583104 (524,288)
// t1 : 2107392  s1 : 2113536
// ao : 2117632  (2,457,600 f32)            [16][600][256]
// qh : 4575232  (2,457,600 halves)         [16][8][600][32] fp16, pre-scaled
// kh : 5804032  (2,457,600 halves)         [16][8][600][32] fp16
// vt : 7032832  (2,621,440 halves)         [16][8][32][640] fp16, transposed
//      cols 600..639 zero-filled by k_proj tail tiles (pO aliases this region)
// end: 8343552 f32 = 33.4 MB
// pH : aliases 2117632 .. 6836224  (3 x 1,572,864)  — consumed before qh/kh/vt written
// pO : aliases 6836224 .. 7884800  (2 x 524,288)

__global__ void k_chain1(const float* __restrict__ resolution,
                         const float* __restrict__ framerate,
                         const float* __restrict__ W1, const float* __restrict__ b1,
                         const float* __restrict__ V1, const float* __restrict__ c1,
                         float* __restrict__ t1, float* __restrict__ s1)
{
    __shared__ float fr[B], re[B];
    int j = threadIdx.x;   // 384 threads
    if (j < B) { fr[j] = framerate[j]; re[j] = resolution[j]; }
    __syncthreads();
    {
        float w0 = W1[j], w1 = W1[D3 + j], bb = b1[j];
        for (int b = 0; b < B; ++b) t1[b*D3 + j] = fr[b]*w0 + re[b]*w1 + bb;
    }
    if (j < INNER) {
        float w0 = V1[j], w1 = V1[INNER + j], bb = c1[j];
        for (int b = 0; b < B; ++b) s1[b*INNER + j] = fr[b]*w0 + re[b]*w1 + bb;
    }
}

__global__ void k_chain2(const float* __restrict__ t1, const float* __restrict__ s1,
                         const float* __restrict__ W2, const float* __restrict__ b2,
                         const float* __restrict__ V2, const float* __restrict__ c2,
                         float* __restrict__ t2, float* __restrict__ s2)
{
    __shared__ float in_s[B*D3];
    int bid = blockIdx.x, tid = threadIdx.x;
    if (bid < 24) {
        for (int i = tid; i < B*D3; i += 256) in_s[i] = t1[i];
        __syncthreads();
        int flat = bid*256 + tid;
        int b = flat / D3, j = flat - b*D3;
        float acc = b2[j];
        #pragma unroll 4
        for (int kk = 0; kk < D3; ++kk)
            acc = fmaf(in_s[b*D3 + kk], W2[kk*D3 + j], acc);
        t2[flat] = acc;
    } else {
        for (int i = tid; i < B*INNER; i += 256) in_s[i] = s1[i];
        __syncthreads();
        int flat = (bid - 24)*256 + tid;
        int b = flat / INNER, j = flat - b*INNER;
        float acc = c2[j];
        #pragma unroll 4
        for (int kk = 0; kk < INNER; ++kk)
            acc = fmaf(in_s[b*INNER + kk], V2[kk*INNER + j], acc);
        s2[flat] = acc;
    }
}

// Split-K hypernet GEMM: grid = (NC/256) x KSG, 512 threads = 2 K-halves.
template<int K, int NC, int KSG>
__global__ __launch_bounds__(512) void k_hyper2(const float* __restrict__ tin,
                                                const float* __restrict__ W,
                                                float* __restrict__ partial)
{
    constexpr int KR = K / KSG;
    constexpr int KH = KR / 2;
    __shared__ float ts[B*KR];
    __shared__ float mrg[B*256];
    int tid = threadIdx.x;
    int cb = blockIdx.x % (NC/256), ksg = blockIdx.x / (NC/256);
    int half = tid >> 8, c = tid & 255;
    int col = cb*256 + c;
    for (int i = tid; i < B*KR; i += 512) {
        int b = i / KR, kk = i - b*KR;
        ts[i] = tin[b*K + ksg*KR + kk];
    }
    __syncthreads();
    float acc[B];
    #pragma unroll
    for (int b = 0; b < B; ++b) acc[b] = 0.f;
    const float* wp = W + (size_t)(ksg*KR + half*KH)*NC + col;
    const int tbase = half*KH;
    #pragma unroll 8
    for (int kk = 0; kk < KH; ++kk) {
        float w = wp[(size_t)kk*NC];
        #pragma unroll
        for (int b = 0; b < B; ++b) acc[b] = fmaf(ts[b*KR + tbase + kk], w, acc[b]);
    }
    if (half) {
        #pragma unroll
        for (int b = 0; b < B; ++b) mrg[b*256 + c] = acc[b];
    }
    __syncthreads();
    if (!half) {
        float* pp = partial + (size_t)ksg*B*NC + col;
        #pragma unroll
        for (int b = 0; b < B; ++b) pp[(size_t)b*NC] = acc[b] + mrg[b*256 + c];
    }
}

template<int NC, int KSG>
__global__ __launch_bounds__(256) void k_reduce(const float* __restrict__ partial,
                                                const float* __restrict__ bias,
                                                float* __restrict__ out)
{
    int i = blockIdx.x*256 + threadIdx.x;
    int col = i % NC;
    float s = bias[col];
    #pragma unroll
    for (int ks = 0; ks < KSG; ++ks) s += partial[(size_t)ks*B*NC + i];
    out[i] = s;
}

// softmax along R-axis of data[b][R][CPB]; COLS*GROUPS = 256 threads
template<int R, int CPB, int COLS, int GROUPS>
__global__ __launch_bounds__(256) void k_softmax2(float* __restrict__ data)
{
    constexpr int RPT = R / GROUPS;
    __shared__ float red[GROUPS][COLS];
    int tid = threadIdx.x;
    int col = tid % COLS, g = tid / COLS;
    int nb = CPB / COLS;
    int b = blockIdx.x / nb, cb = blockIdx.x % nb;
    float* p = data + (size_t)b*R*CPB + (size_t)g*RPT*CPB + cb*COLS + col;
    float vals[RPT];
    float m = -1e30f;
    #pragma unroll 4
    for (int r = 0; r < RPT; ++r) { vals[r] = p[(size_t)r*CPB]; m = fmaxf(m, vals[r]); }
    red[g][col] = m;
    __syncthreads();
    float M = red[0][col];
    #pragma unroll
    for (int gg = 1; gg < GROUPS; ++gg) M = fmaxf(M, red[gg][col]);
    __syncthreads();
    float s = 0.f;
    #pragma unroll 4
    for (int r = 0; r < RPT; ++r) { vals[r] = __expf(vals[r] - M); s += vals[r]; }
    red[g][col] = s;
    __syncthreads();
    float S = 0.f;
    #pragma unroll
    for (int gg = 0; gg < GROUPS; ++gg) S += red[gg][col];
    float inv = 1.f / S;
    #pragma unroll 4
    for (int r = 0; r < RPT; ++r) p[(size_t)r*CPB] = vals[r] * inv;
}

// x @ qkvw -> q,k (fp16 row-major, q pre-scaled) and v (fp16 transposed [d][n])
__global__ __launch_bounds__(768) void k_proj(const float* __restrict__ x,
                                              const float* __restrict__ qkvw,
                                              _Float16* __restrict__ qh,
                                              _Float16* __restrict__ kh,
                                              _Float16* __restrict__ vt)
{
    __shared__ float4 xs4[24*32];
    int b = blockIdx.x / 25, t0 = (blockIdx.x % 25)*24;
    int tid = threadIdx.x;
    const float4* xp4 = (const float4*)(x + ((size_t)b*N + t0)*DIM);
    xs4[tid] = xp4[tid];              // 24*32 = 768 = blockDim
    __syncthreads();
    float acc[24];
    #pragma unroll
    for (int r = 0; r < 24; ++r) acc[r] = 0.f;
    const float* wp = qkvw + (size_t)b*NC_H + tid;
    for (int d4 = 0; d4 < 32; ++d4) {
        float w0 = wp[(size_t)(4*d4)*768];
        float w1 = wp[(size_t)(4*d4+1)*768];
        float w2 = wp[(size_t)(4*d4+2)*768];
        float w3 = wp[(size_t)(4*d4+3)*768];
        #pragma unroll
        for (int r = 0; r < 24; ++r) {
            float4 xv = xs4[r*32 + d4];
            acc[r] = fmaf(xv.x, w0, fmaf(xv.y, w1, fmaf(xv.z, w2, fmaf(xv.w, w3, acc[r]))));
        }
    }
    int which = tid >> 8;
    int e = tid & 255;
    int hh = e >> 5, dh = e & 31;
    const float scale = 0.17677669529663687f;   // 32^-0.5 folded into Q
    if (which == 0) {
        _Float16* qp = qh + ((size_t)(b*HEADS + hh)*N + t0)*DH + dh;
        #pragma unroll
        for (int r = 0; r < 24; ++r) qp[r*DH] = (_Float16)(acc[r]*scale);
    } else if (which == 1) {
        _Float16* kp = kh + ((size_t)(b*HEADS + hh)*N + t0)*DH + dh;
        #pragma unroll
        for (int r = 0; r < 24; ++r) kp[r*DH] = (_Float16)acc[r];
    } else {
        _Float16* vp = vt + ((size_t)(b*HEADS + hh)*DH + dh)*640 + t0;
        #pragma unroll
        for (int r = 0; r < 24; ++r) vp[r] = (_Float16)acc[r];
        if (t0 == 576) {
            #pragma unroll
            for (int r = 24; r < 64; ++r) vp[r] = (_Float16)0.f;
        }
    }
}

static __device__ inline unsigned pk2(float a, float b) {
    auto t = __builtin_amdgcn_cvt_pkrtz(a, b);   // __fp16 ext_vector(2)
    return __builtin_bit_cast(unsigned, t);
}

// MFMA flash attention v4.  Block = 4 waves = 4 heads sharing one (b, q-chunk);
// wave = 16 q-rows x 600 keys.  Head-independent mask tile [16][64] f32 staged
// cooperatively in LDS (coalesced float4, stride-65), DOUBLE-BUFFERED: next
// tile's global loads issue before compute, ds_write after -> latency hidden.
// S^T = mfma(K, Q^T), out^T = mfma(V^T, P^T): softmax lane-local on q = lane&15.
// Grid bid = qc*32 + b*2 + hg: the 38 K/V-sharing blocks land in one XCD class.
__global__ __launch_bounds__(256) void k_attn4(const _Float16* __restrict__ qh,
                                               const _Float16* __restrict__ kh,
                                               const _Float16* __restrict__ vt,
                                               const float* __restrict__ mask,
                                               float* __restrict__ ao)
{
    __shared__ float mbuf[2][16][65];
    __shared__ __align__(16) _Float16 plds[4][16][72];
    int bid = blockIdx.x;
    int qc = bid / 32, r2 = bid % 32;
    int b = r2 >> 1, hg = r2 & 1;
    int tid = threadIdx.x;
    int w = tid >> 6, lane = tid & 63;
    int ql = lane & 15, g = lane >> 4;
    int h = hg*4 + w;
    int q0 = qc*16;
    size_t bh = (size_t)(b*HEADS + h);
    const _Float16* Qb  = qh + bh*(size_t)(N*DH);
    const _Float16* Kb  = kh + bh*(size_t)(N*DH);
    const _Float16* Vtb = vt + bh*(size_t)(DH*640);

    int qrow = q0 + ql;
    int qr = qrow > 599 ? 599 : qrow;
    f16x8 qf = *(const f16x8*)(Qb + (size_t)qr*DH + g*8);

    // mask staging: wave w owns local rows w*4 .. w*4+3; lane -> (row, float4-col)
    int rl = w*4 + (lane >> 4);          // local tile row 0..15
    int mcol = (lane & 15)*4;            // float col 0..60
    int mgr = q0 + rl; if (mgr > 599) mgr = 599;
    const float* mgp = mask + ((size_t)b*N + mgr)*N;

    float M = -1e30f, S = 0.f;
    f32x4 acc[2];
    acc[0] = (f32x4){0.f,0.f,0.f,0.f};
    acc[1] = (f32x4){0.f,0.f,0.f,0.f};

    // prologue: stage chunk 0
    {
        int c0 = mcol; if (c0 > 596) c0 = 596;
        float4 mv = *(const float4*)(mgp + c0);
        mbuf[0][rl][mcol+0] = mv.x;
        mbuf[0][rl][mcol+1] = mv.y;
        mbuf[0][rl][mcol+2] = mv.z;
        mbuf[0][rl][mcol+3] = mv.w;
    }
    __syncthreads();

    for (int c = 0; c < 10; ++c) {
        int k0 = c*64;
        int cur = c & 1;
        // issue next mask tile's global load early (latency hides under compute)
        float4 mnext;
        if (c < 9) {
            int cg = (c+1)*64 + mcol; if (cg > 596) cg = 596;
            mnext = *(const float4*)(mgp + cg);
        }
        // ---- QK^T: 4 key-subtiles ----
        f32x4 st[4];
        #pragma unroll
        for (int t = 0; t < 4; ++t) {
            int kr = k0 + 16*t + ql; if (kr > 599) kr = 599;
            f16x8 kf = *(const f16x8*)(Kb + (size_t)kr*DH + g*8);
            st[t] = __builtin_amdgcn_mfma_f32_16x16x32_f16(
                kf, qf, (f32x4){0.f,0.f,0.f,0.f}, 0, 0, 0);
        }
        // ---- softmax (lane-local on q=ql; reduce over g via 2 shfl) ----
        float tm = -1e30f;
        #pragma unroll
        for (int t = 0; t < 4; ++t) {
            #pragma unroll
            for (int r = 0; r < 4; ++r) {
                int key = k0 + 16*t + 4*g + r;
                float sv = st[t][r];
                if (key >= N) sv = -1e30f;
                st[t][r] = sv;
                tm = fmaxf(tm, sv);
            }
        }
        tm = fmaxf(tm, __shfl_xor(tm, 16));
        tm = fmaxf(tm, __shfl_xor(tm, 32));
        float Mn = fmaxf(M, tm);
        float scl = __expf(M - Mn);
        M = Mn;
        S *= scl;
        acc[0] *= scl;
        acc[1] *= scl;
        float ssum = 0.f;
        #pragma unroll
        for (int t = 0; t < 4; ++t) {
            int cb4 = 16*t + 4*g;
            float e0 = __expf(st[t][0] - Mn);
            float e1 = __expf(st[t][1] - Mn);
            float e2 = __expf(st[t][2] - Mn);
            float e3 = __expf(st[t][3] - Mn);
            ssum += (e0 + e1) + (e2 + e3);
            float m0 = mbuf[cur][ql][cb4+0];
            float m1 = mbuf[cur][ql][cb4+1];
            float m2 = mbuf[cur][ql][cb4+2];
            float m3 = mbuf[cur][ql][cb4+3];
            *(unsigned*)&plds[w][ql][cb4]     = pk2(e0*m0, e1*m1);
            *(unsigned*)&plds[w][ql][cb4 + 2] = pk2(e2*m2, e3*m3);
        }
        ssum += __shfl_xor(ssum, 16);
        ssum += __shfl_xor(ssum, 32);
        S += ssum;
        // ---- PV: out^T += V^T-frag x P^T-frag ----
        #pragma unroll
        for (int win = 0; win < 2; ++win) {
            f16x8 pf = *(const f16x8*)&plds[w][ql][win*32 + g*8];
            #pragma unroll
            for (int dt = 0; dt < 2; ++dt) {
                f16x8 vf = *(const f16x8*)(Vtb + (size_t)(dt*16 + ql)*640 + k0 + win*32 + g*8);
                acc[dt] = __builtin_amdgcn_mfma_f32_16x16x32_f16(vf, pf, acc[dt], 0, 0, 0);
            }
        }
        // ---- write next mask tile (global load has had compute-time to land) ----
        if (c < 9) {
            int nb = cur ^ 1;
            mbuf[nb][rl][mcol+0] = mnext.x;
            mbuf[nb][rl][mcol+1] = mnext.y;
            mbuf[nb][rl][mcol+2] = mnext.z;
            mbuf[nb][rl][mcol+3] = mnext.w;
        }
        __syncthreads();   // next buffer visible; current buffer free for overwrite
    }

    // ---- epilogue: out[q][d] = acc^T[d][q] / S[q] ----
    if (qrow < N) {
        float inv = 1.f / S;
        float* o = ao + ((size_t)b*N + qrow)*INNER + h*DH;
        #pragma unroll
        for (int dt = 0; dt < 2; ++dt)
            #pragma unroll
            for (int r = 0; r < 4; ++r)
                o[dt*16 + 4*g + r] = acc[dt][r] * inv;
    }
}

__global__ __launch_bounds__(128) void k_final(const float* __restrict__ ao,
                                               const float* __restrict__ ow,
                                               float* __restrict__ out)
{
    __shared__ float4 os4[12*64];
    int b = blockIdx.x / 50, t0 = (blockIdx.x % 50)*12;
    int tid = threadIdx.x;
    const float4* ap4 = (const float4*)(ao + ((size_t)b*N + t0)*INNER);
    for (int i = tid; i < 12*64; i += 128) os4[i] = ap4[i];
    __syncthreads();
    float acc[12];
    #pragma unroll
    for (int r = 0; r < 12; ++r) acc[r] = 0.f;
    const float* wp = ow + (size_t)b*NC_O + tid;
    for (int i4 = 0; i4 < 64; ++i4) {
        float w0 = wp[(size_t)(4*i4)*DIM];
        float w1 = wp[(size_t)(4*i4+1)*DIM];
        float w2 = wp[(size_t)(4*i4+2)*DIM];
        float w3 = wp[(size_t)(4*i4+3)*DIM];
        #pragma unroll
        for (int r = 0; r < 12; ++r) {
            float4 av = os4[r*64 + i4];
            acc[r] = fmaf(av.x, w0, fmaf(av.y, w1, fmaf(av.z, w2, fmaf(av.w, w3, acc[r]))));
        }
    }
    float* op = out + ((size_t)b*N + t0)*DIM + tid;
    #pragma unroll
    for (int r = 0; r < 12; ++r) op[r*DIM] = acc[r];
}

extern "C" void kernel_launch(void* const* d_in, const int* in_sizes, int n_in,
                              void* d_out, int out_size, void* d_ws, size_t ws_size,
                              hipStream_t stream)
{
    const float* x          = (const float*)d_in[0];
    const float* mask       = (const float*)d_in[1];
    const float* resolution = (const float*)d_in[2];
    const float* framerate  = (const float*)d_in[3];
    const float* W1 = (const float*)d_in[4];
    const float* b1 = (const float*)d_in[5];
    const float* W2 = (const float*)d_in[6];
    const float* b2 = (const float*)d_in[7];
    const float* W3 = (const float*)d_in[8];
    const float* b3 = (const float*)d_in[9];
    const float* V1 = (const float*)d_in[10];
    const float* c1 = (const float*)d_in[11];
    const float* V2 = (const float*)d_in[12];
    const float* c2 = (const float*)d_in[13];
    const float* V3 = (const float*)d_in[14];
    const float* c3 = (const float*)d_in[15];

    float* ws = (float*)d_ws;
    float* t2 = ws;
    float* s2 = ws + 6144;
    float* h  = ws + 10240;
    float* ow = ws + 1583104;
    float* t1 = ws + 2107392;
    float* s1 = ws + 2113536;
    float* ao = ws + 2117632;
    float* pH = ws + 2117632;               // 3 x 1,572,864 (aliases ao/qh)
    float* pO = ws + 6836224;               // 2 x 524,288   (aliases kh/vt)
    _Float16* qh = (_Float16*)(ws + 4575232);
    _Float16* kh = (_Float16*)(ws + 5804032);
    _Float16* vt = (_Float16*)(ws + 7032832);
    float* out = (float*)d_out;

    hipLaunchKernelGGL(k_chain1, dim3(1), dim3(384), 0, stream,
                       resolution, framerate, W1, b1, V1, c1, t1, s1);
    hipLaunchKernelGGL(k_chain2, dim3(40), dim3(256), 0, stream,
                       t1, s1, W2, b2, V2, c2, t2, s2);
    hipLaunchKernelGGL((k_hyper2<D3, NC_H, 3>), dim3((NC_H/256)*3), dim3(512), 0, stream,
                       t2, W3, pH);
    hipLaunchKernelGGL((k_hyper2<INNER, NC_O, 2>), dim3((NC_O/256)*2), dim3(512), 0, stream,
                       s2, V3, pO);
    hipLaunchKernelGGL((k_reduce<NC_H, 3>), dim3(B*NC_H/256), dim3(256), 0, stream,
                       pH, b3, h);
    hipLaunchKernelGGL((k_reduce<NC_O, 2>), dim3(B*NC_O/256), dim3(256), 0, stream,
                       pO, c3, ow);
    hipLaunchKernelGGL((k_softmax2<DIM, 3*INNER, 64, 4>), dim3(B*12), dim3(256), 0, stream, h);
    hipLaunchKernelGGL((k_softmax2<INNER, DIM, 32, 8>), dim3(B*4), dim3(256), 0, stream, ow);
    hipLaunchKernelGGL(k_proj, dim3(B*25), dim3(768), 0, stream, x, h, qh, kh, vt);
    hipLaunchKernelGGL(k_attn4, dim3(38*32), dim3(256), 0, stream, qh, kh, vt, mask, ao);
    hipLaunchKernelGGL(k_final, dim3(B*50), dim3(128), 0, stream, ao, ow, out);
}

// Round 8
// 259.170 us; speedup vs baseline: 4.3334x; 1.1097x over previous
//
#include <hip/hip_runtime.h>
#include <hip/hip_bf16.h>
#include <math.h>

#define B 16
#define N 600
#define DIM 128
#define HEADS 8
#define DH 32
#define INNER 256
#define D3 384
#define NC_H (D3*INNER)   /* 98304 */
#define NC_O (INNER*DIM)  /* 32768 */

typedef _Float16 f16x8 __attribute__((ext_vector_type(8)));
typedef float    f32x4 __attribute__((ext_vector_type(4)));

// ---------------- ws layout (float offsets) ----------------
// t2 : 0        s2 : 6144     h : 10240 (1,572,864)   ow : 1583104 (524,288)
// t1 : 2107392  s1 : 2113536
// ao : 2117632  (2,457,600 f32)            [16][600][256]
// qh : 4575232  (2,457,600 halves)         [16][8][600][32] fp16, pre-scaled
// kh : 5804032  (2,457,600 halves)         [16][8][600][32] fp16
// vt : 7032832  (2,621,440 halves)         [16][8][32][640] fp16, transposed
//      cols 600..639 zero-filled by k_proj tail tiles (pH aliases this region)
// pH : 2117632 .. 8409088   (4 x 1,572,864) — consumed by reduceH before k_proj
// pO : 8409088 .. 9457664   (2 x 524,288)   — beyond vt end (8343552), no alias
// t2T: 9457664 .. 9463808   [384][16] k-major copy of t2
// max used: 9,463,808 f32 = 37.9 MB  (round-1 proved >= 47.8 MB available)

__global__ void k_chain1(const float* __restrict__ resolution,
                         const float* __restrict__ framerate,
                         const float* __restrict__ W1, const float* __restrict__ b1,
                         const float* __restrict__ V1, const float* __restrict__ c1,
                         float* __restrict__ t1, float* __restrict__ s1)
{
    __shared__ float fr[B], re[B];
    int j = threadIdx.x;   // 384 threads
    if (j < B) { fr[j] = framerate[j]; re[j] = resolution[j]; }
    __syncthreads();
    {
        float w0 = W1[j], w1 = W1[D3 + j], bb = b1[j];
        for (int b = 0; b < B; ++b) t1[b*D3 + j] = fr[b]*w0 + re[b]*w1 + bb;
    }
    if (j < INNER) {
        float w0 = V1[j], w1 = V1[INNER + j], bb = c1[j];
        for (int b = 0; b < B; ++b) s1[b*INNER + j] = fr[b]*w0 + re[b]*w1 + bb;
    }
}

__global__ void k_chain2(const float* __restrict__ t1, const float* __restrict__ s1,
                         const float* __restrict__ W2, const float* __restrict__ b2,
                         const float* __restrict__ V2, const float* __restrict__ c2,
                         float* __restrict__ t2, float* __restrict__ t2T,
                         float* __restrict__ s2)
{
    __shared__ float in_s[B*D3];
    int bid = blockIdx.x, tid = threadIdx.x;
    if (bid < 24) {
        for (int i = tid; i < B*D3; i += 256) in_s[i] = t1[i];
        __syncthreads();
        int flat = bid*256 + tid;
        int b = flat / D3, j = flat - b*D3;
        float acc = b2[j];
        #pragma unroll 4
        for (int kk = 0; kk < D3; ++kk)
            acc = fmaf(in_s[b*D3 + kk], W2[kk*D3 + j], acc);
        t2[flat] = acc;
        t2T[j*B + b] = acc;           // k-major copy for k_hyper3 scalar loads
    } else {
        for (int i = tid; i < B*INNER; i += 256) in_s[i] = s1[i];
        __syncthreads();
        int flat = (bid - 24)*256 + tid;
        int b = flat / INNER, j = flat - b*INNER;
        float acc = c2[j];
        #pragma unroll 4
        for (int kk = 0; kk < INNER; ++kk)
            acc = fmaf(in_s[b*INNER + kk], V2[kk*INNER + j], acc);
        s2[flat] = acc;
    }
}

// Split-K streaming GEMM for W3: thread = 2 cols, block = 512 cols, KSG K-splits.
// ts comes from t2T[k][16] via wave-uniform reads -> s_load (no LDS, no ds_read).
// W loads float2, software-pipelined depth 4 (static names, rule-#20 safe).
template<int K, int NC, int KSG>
__global__ __launch_bounds__(256) void k_hyper3(const float* __restrict__ t2T,
                                                const float* __restrict__ W,
                                                float* __restrict__ partial)
{
    constexpr int KR = K / KSG;
    constexpr int NCB = NC / 512;
    int tid = threadIdx.x;
    int cb = blockIdx.x % NCB, ksg = blockIdx.x / NCB;
    int col = cb*512 + tid*2;
    const float* wp = W + (size_t)(ksg*KR)*NC + col;
    const float* tp = t2T + ksg*KR*B;

    float2 acc[B];
    #pragma unroll
    for (int b = 0; b < B; ++b) acc[b] = make_float2(0.f, 0.f);

    float2 w0 = *(const float2*)(wp);
    float2 w1 = *(const float2*)(wp + (size_t)1*NC);
    float2 w2 = *(const float2*)(wp + (size_t)2*NC);
    float2 w3 = *(const float2*)(wp + (size_t)3*NC);
    for (int kk = 0; kk < KR; kk += 4) {
        float2 c0 = w0, c1 = w1, c2 = w2, c3 = w3;
        if (kk + 4 < KR) {
            const float* wn = wp + (size_t)(kk+4)*NC;
            w0 = *(const float2*)(wn);
            w1 = *(const float2*)(wn + (size_t)1*NC);
            w2 = *(const float2*)(wn + (size_t)2*NC);
            w3 = *(const float2*)(wn + (size_t)3*NC);
        }
        const float* ta = tp + (kk+0)*B;
        const float* tb = tp + (kk+1)*B;
        const float* tc = tp + (kk+2)*B;
        const float* td = tp + (kk+3)*B;
        #pragma unroll
        for (int b = 0; b < B; ++b) {
            float va = ta[b], vb = tb[b], vc = tc[b], vd = td[b];
            acc[b].x = fmaf(va, c0.x, acc[b].x);
            acc[b].y = fmaf(va, c0.y, acc[b].y);
            acc[b].x = fmaf(vb, c1.x, acc[b].x);
            acc[b].y = fmaf(vb, c1.y, acc[b].y);
            acc[b].x = fmaf(vc, c2.x, acc[b].x);
            acc[b].y = fmaf(vc, c2.y, acc[b].y);
            acc[b].x = fmaf(vd, c3.x, acc[b].x);
            acc[b].y = fmaf(vd, c3.y, acc[b].y);
        }
    }
    float* pp = partial + (size_t)ksg*B*NC + col;
    #pragma unroll
    for (int b = 0; b < B; ++b)
        *(float2*)(pp + (size_t)b*NC) = acc[b];
}

// (kept for the small V3 GEMM) grid = (NC/256) x KSG, 512 threads = 2 K-halves.
template<int K, int NC, int KSG>
__global__ __launch_bounds__(512) void k_hyper2(const float* __restrict__ tin,
                                                const float* __restrict__ W,
                                                float* __restrict__ partial)
{
    constexpr int KR = K / KSG;
    constexpr int KH = KR / 2;
    __shared__ float ts[B*KR];
    __shared__ float mrg[B*256];
    int tid = threadIdx.x;
    int cb = blockIdx.x % (NC/256), ksg = blockIdx.x / (NC/256);
    int half = tid >> 8, c = tid & 255;
    int col = cb*256 + c;
    for (int i = tid; i < B*KR; i += 512) {
        int b = i / KR, kk = i - b*KR;
        ts[i] = tin[b*K + ksg*KR + kk];
    }
    __syncthreads();
    float acc[B];
    #pragma unroll
    for (int b = 0; b < B; ++b) acc[b] = 0.f;
    const float* wp = W + (size_t)(ksg*KR + half*KH)*NC + col;
    const int tbase = half*KH;
    #pragma unroll 8
    for (int kk = 0; kk < KH; ++kk) {
        float w = wp[(size_t)kk*NC];
        #pragma unroll
        for (int b = 0; b < B; ++b) acc[b] = fmaf(ts[b*KR + tbase + kk], w, acc[b]);
    }
    if (half) {
        #pragma unroll
        for (int b = 0; b < B; ++b) mrg[b*256 + c] = acc[b];
    }
    __syncthreads();
    if (!half) {
        float* pp = partial + (size_t)ksg*B*NC + col;
        #pragma unroll
        for (int b = 0; b < B; ++b) pp[(size_t)b*NC] = acc[b] + mrg[b*256 + c];
    }
}

template<int NC, int KSG>
__global__ __launch_bounds__(256) void k_reduce(const float* __restrict__ partial,
                                                const float* __restrict__ bias,
                                                float* __restrict__ out)
{
    int i = blockIdx.x*256 + threadIdx.x;
    int col = i % NC;
    float s = bias[col];
    #pragma unroll
    for (int ks = 0; ks < KSG; ++ks) s += partial[(size_t)ks*B*NC + i];
    out[i] = s;
}

// softmax along R-axis of data[b][R][CPB]; COLS*GROUPS = 256 threads
template<int R, int CPB, int COLS, int GROUPS>
__global__ __launch_bounds__(256) void k_softmax2(float* __restrict__ data)
{
    constexpr int RPT = R / GROUPS;
    __shared__ float red[GROUPS][COLS];
    int tid = threadIdx.x;
    int col = tid % COLS, g = tid / COLS;
    int nb = CPB / COLS;
    int b = blockIdx.x / nb, cb = blockIdx.x % nb;
    float* p = data + (size_t)b*R*CPB + (size_t)g*RPT*CPB + cb*COLS + col;
    float vals[RPT];
    float m = -1e30f;
    #pragma unroll 4
    for (int r = 0; r < RPT; ++r) { vals[r] = p[(size_t)r*CPB]; m = fmaxf(m, vals[r]); }
    red[g][col] = m;
    __syncthreads();
    float M = red[0][col];
    #pragma unroll
    for (int gg = 1; gg < GROUPS; ++gg) M = fmaxf(M, red[gg][col]);
    __syncthreads();
    float s = 0.f;
    #pragma unroll 4
    for (int r = 0; r < RPT; ++r) { vals[r] = __expf(vals[r] - M); s += vals[r]; }
    red[g][col] = s;
    __syncthreads();
    float S = 0.f;
    #pragma unroll
    for (int gg = 0; gg < GROUPS; ++gg) S += red[gg][col];
    float inv = 1.f / S;
    #pragma unroll 4
    for (int r = 0; r < RPT; ++r) p[(size_t)r*CPB] = vals[r] * inv;
}

// x @ qkvw -> q,k (fp16 row-major, q pre-scaled) and v (fp16 transposed [d][n])
__global__ __launch_bounds__(768) void k_proj(const float* __restrict__ x,
                                              const float* __restrict__ qkvw,
                                              _Float16* __restrict__ qh,
                                              _Float16* __restrict__ kh,
                                              _Float16* __restrict__ vt)
{
    __shared__ float4 xs4[24*32];
    int b = blockIdx.x / 25, t0 = (blockIdx.x % 25)*24;
    int tid = threadIdx.x;
    const float4* xp4 = (const float4*)(x + ((size_t)b*N + t0)*DIM);
    xs4[tid] = xp4[tid];              // 24*32 = 768 = blockDim
    __syncthreads();
    float acc[24];
    #pragma unroll
    for (int r = 0; r < 24; ++r) acc[r] = 0.f;
    const float* wp = qkvw + (size_t)b*NC_H + tid;
    for (int d4 = 0; d4 < 32; ++d4) {
        float w0 = wp[(size_t)(4*d4)*768];
        float w1 = wp[(size_t)(4*d4+1)*768];
        float w2 = wp[(size_t)(4*d4+2)*768];
        float w3 = wp[(size_t)(4*d4+3)*768];
        #pragma unroll
        for (int r = 0; r < 24; ++r) {
            float4 xv = xs4[r*32 + d4];
            acc[r] = fmaf(xv.x, w0, fmaf(xv.y, w1, fmaf(xv.z, w2, fmaf(xv.w, w3, acc[r]))));
        }
    }
    int which = tid >> 8;
    int e = tid & 255;
    int hh = e >> 5, dh = e & 31;
    const float scale = 0.17677669529663687f;   // 32^-0.5 folded into Q
    if (which == 0) {
        _Float16* qp = qh + ((size_t)(b*HEADS + hh)*N + t0)*DH + dh;
        #pragma unroll
        for (int r = 0; r < 24; ++r) qp[r*DH] = (_Float16)(acc[r]*scale);
    } else if (which == 1) {
        _Float16* kp = kh + ((size_t)(b*HEADS + hh)*N + t0)*DH + dh;
        #pragma unroll
        for (int r = 0; r < 24; ++r) kp[r*DH] = (_Float16)acc[r];
    } else {
        _Float16* vp = vt + ((size_t)(b*HEADS + hh)*DH + dh)*640 + t0;
        #pragma unroll
        for (int r = 0; r < 24; ++r) vp[r] = (_Float16)acc[r];
        if (t0 == 576) {
            #pragma unroll
            for (int r = 24; r < 64; ++r) vp[r] = (_Float16)0.f;
        }
    }
}

static __device__ inline unsigned pk2(float a, float b) {
    auto t = __builtin_amdgcn_cvt_pkrtz(a, b);   // __fp16 ext_vector(2)
    return __builtin_bit_cast(unsigned, t);
}

// MFMA flash attention v4.  Block = 4 waves = 4 heads sharing one (b, q-chunk);
// wave = 16 q-rows x 600 keys.  Head-independent mask tile [16][64] f32 staged
// cooperatively in LDS, double-buffered.  S^T = mfma(K, Q^T), out^T = mfma(V^T, P^T).
__global__ __launch_bounds__(256) void k_attn4(const _Float16* __restrict__ qh,
                                               const _Float16* __restrict__ kh,
                                               const _Float16* __restrict__ vt,
                                               const float* __restrict__ mask,
                                               float* __restrict__ ao)
{
    __shared__ float mbuf[2][16][65];
    __shared__ __align__(16) _Float16 plds[4][16][72];
    int bid = blockIdx.x;
    int qc = bid / 32, r2 = bid % 32;
    int b = r2 >> 1, hg = r2 & 1;
    int tid = threadIdx.x;
    int w = tid >> 6, lane = tid & 63;
    int ql = lane & 15, g = lane >> 4;
    int h = hg*4 + w;
    int q0 = qc*16;
    size_t bh = (size_t)(b*HEADS + h);
    const _Float16* Qb  = qh + bh*(size_t)(N*DH);
    const _Float16* Kb  = kh + bh*(size_t)(N*DH);
    const _Float16* Vtb = vt + bh*(size_t)(DH*640);

    int qrow = q0 + ql;
    int qr = qrow > 599 ? 599 : qrow;
    f16x8 qf = *(const f16x8*)(Qb + (size_t)qr*DH + g*8);

    int rl = w*4 + (lane >> 4);          // local tile row 0..15
    int mcol = (lane & 15)*4;            // float col 0..60
    int mgr = q0 + rl; if (mgr > 599) mgr = 599;
    const float* mgp = mask + ((size_t)b*N + mgr)*N;

    float M = -1e30f, S = 0.f;
    f32x4 acc[2];
    acc[0] = (f32x4){0.f,0.f,0.f,0.f};
    acc[1] = (f32x4){0.f,0.f,0.f,0.f};

    {
        int c0 = mcol; if (c0 > 596) c0 = 596;
        float4 mv = *(const float4*)(mgp + c0);
        mbuf[0][rl][mcol+0] = mv.x;
        mbuf[0][rl][mcol+1] = mv.y;
        mbuf[0][rl][mcol+2] = mv.z;
        mbuf[0][rl][mcol+3] = mv.w;
    }
    __syncthreads();

    for (int c = 0; c < 10; ++c) {
        int k0 = c*64;
        int cur = c & 1;
        float4 mnext;
        if (c < 9) {
            int cg = (c+1)*64 + mcol; if (cg > 596) cg = 596;
            mnext = *(const float4*)(mgp + cg);
        }
        f32x4 st[4];
        #pragma unroll
        for (int t = 0; t < 4; ++t) {
            int kr = k0 + 16*t + ql; if (kr > 599) kr = 599;
            f16x8 kf = *(const f16x8*)(Kb + (size_t)kr*DH + g*8);
            st[t] = __builtin_amdgcn_mfma_f32_16x16x32_f16(
                kf, qf, (f32x4){0.f,0.f,0.f,0.f}, 0, 0, 0);
        }
        float tm = -1e30f;
        #pragma unroll
        for (int t = 0; t < 4; ++t) {
            #pragma unroll
            for (int r = 0; r < 4; ++r) {
                int key = k0 + 16*t + 4*g + r;
                float sv = st[t][r];
                if (key >= N) sv = -1e30f;
                st[t][r] = sv;
                tm = fmaxf(tm, sv);
            }
        }
        tm = fmaxf(tm, __shfl_xor(tm, 16));
        tm = fmaxf(tm, __shfl_xor(tm, 32));
        float Mn = fmaxf(M, tm);
        float scl = __expf(M - Mn);
        M = Mn;
        S *= scl;
        acc[0] *= scl;
        acc[1] *= scl;
        float ssum = 0.f;
        #pragma unroll
        for (int t = 0; t < 4; ++t) {
            int cb4 = 16*t + 4*g;
            float e0 = __expf(st[t][0] - Mn);
            float e1 = __expf(st[t][1] - Mn);
            float e2 = __expf(st[t][2] - Mn);
            float e3 = __expf(st[t][3] - Mn);
            ssum += (e0 + e1) + (e2 + e3);
            float m0 = mbuf[cur][ql][cb4+0];
            float m1 = mbuf[cur][ql][cb4+1];
            float m2 = mbuf[cur][ql][cb4+2];
            float m3 = mbuf[cur][ql][cb4+3];
            *(unsigned*)&plds[w][ql][cb4]     = pk2(e0*m0, e1*m1);
            *(unsigned*)&plds[w][ql][cb4 + 2] = pk2(e2*m2, e3*m3);
        }
        ssum += __shfl_xor(ssum, 16);
        ssum += __shfl_xor(ssum, 32);
        S += ssum;
        #pragma unroll
        for (int win = 0; win < 2; ++win) {
            f16x8 pf = *(const f16x8*)&plds[w][ql][win*32 + g*8];
            #pragma unroll
            for (int dt = 0; dt < 2; ++dt) {
                f16x8 vf = *(const f16x8*)(Vtb + (size_t)(dt*16 + ql)*640 + k0 + win*32 + g*8);
                acc[dt] = __builtin_amdgcn_mfma_f32_16x16x32_f16(vf, pf, acc[dt], 0, 0, 0);
            }
        }
        if (c < 9) {
            int nb = cur ^ 1;
            mbuf[nb][rl][mcol+0] = mnext.x;
            mbuf[nb][rl][mcol+1] = mnext.y;
            mbuf[nb][rl][mcol+2] = mnext.z;
            mbuf[nb][rl][mcol+3] = mnext.w;
        }
        __syncthreads();
    }

    if (qrow < N) {
        float inv = 1.f / S;
        float* o = ao + ((size_t)b*N + qrow)*INNER + h*DH;
        #pragma unroll
        for (int dt = 0; dt < 2; ++dt)
            #pragma unroll
            for (int r = 0; r < 4; ++r)
                o[dt*16 + 4*g + r] = acc[dt][r] * inv;
    }
}

__global__ __launch_bounds__(128) void k_final(const float* __restrict__ ao,
                                               const float* __restrict__ ow,
                                               float* __restrict__ out)
{
    __shared__ float4 os4[12*64];
    int b = blockIdx.x / 50, t0 = (blockIdx.x % 50)*12;
    int tid = threadIdx.x;
    const float4* ap4 = (const float4*)(ao + ((size_t)b*N + t0)*INNER);
    for (int i = tid; i < 12*64; i += 128) os4[i] = ap4[i];
    __syncthreads();
    float acc[12];
    #pragma unroll
    for (int r = 0; r < 12; ++r) acc[r] = 0.f;
    const float* wp = ow + (size_t)b*NC_O + tid;
    for (int i4 = 0; i4 < 64; ++i4) {
        float w0 = wp[(size_t)(4*i4)*DIM];
        float w1 = wp[(size_t)(4*i4+1)*DIM];
        float w2 = wp[(size_t)(4*i4+2)*DIM];
        float w3 = wp[(size_t)(4*i4+3)*DIM];
        #pragma unroll
        for (int r = 0; r < 12; ++r) {
            float4 av = os4[r*64 + i4];
            acc[r] = fmaf(av.x, w0, fmaf(av.y, w1, fmaf(av.z, w2, fmaf(av.w, w3, acc[r]))));
        }
    }
    float* op = out + ((size_t)b*N + t0)*DIM + tid;
    #pragma unroll
    for (int r = 0; r < 12; ++r) op[r*DIM] = acc[r];
}

extern "C" void kernel_launch(void* const* d_in, const int* in_sizes, int n_in,
                              void* d_out, int out_size, void* d_ws, size_t ws_size,
                              hipStream_t stream)
{
    const float* x          = (const float*)d_in[0];
    const float* mask       = (const float*)d_in[1];
    const float* resolution = (const float*)d_in[2];
    const float* framerate  = (const float*)d_in[3];
    const float* W1 = (const float*)d_in[4];
    const float* b1 = (const float*)d_in[5];
    const float* W2 = (const float*)d_in[6];
    const float* b2 = (const float*)d_in[7];
    const float* W3 = (const float*)d_in[8];
    const float* b3 = (const float*)d_in[9];
    const float* V1 = (const float*)d_in[10];
    const float* c1 = (const float*)d_in[11];
    const float* V2 = (const float*)d_in[12];
    const float* c2 = (const float*)d_in[13];
    const float* V3 = (const float*)d_in[14];
    const float* c3 = (const float*)d_in[15];

    float* ws = (float*)d_ws;
    float* t2 = ws;
    float* s2 = ws + 6144;
    float* h  = ws + 10240;
    float* ow = ws + 1583104;
    float* t1 = ws + 2107392;
    float* s1 = ws + 2113536;
    float* ao = ws + 2117632;
    float* pH = ws + 2117632;               // 4 x 1,572,864 (aliases ao/qh/kh/vt)
    float* pO = ws + 8409088;               // 2 x 524,288 (past vt end)
    float* t2T = ws + 9457664;              // [384][16]
    _Float16* qh = (_Float16*)(ws + 4575232);
    _Float16* kh = (_Float16*)(ws + 5804032);
    _Float16* vt = (_Float16*)(ws + 7032832);
    float* out = (float*)d_out;

    hipLaunchKernelGGL(k_chain1, dim3(1), dim3(384), 0, stream,
                       resolution, framerate, W1, b1, V1, c1, t1, s1);
    hipLaunchKernelGGL(k_chain2, dim3(40), dim3(256), 0, stream,
                       t1, s1, W2, b2, V2, c2, t2, t2T, s2);
    hipLaunchKernelGGL((k_hyper3<D3, NC_H, 4>), dim3((NC_H/512)*4), dim3(256), 0, stream,
                       t2T, W3, pH);
    hipLaunchKernelGGL((k_hyper2<INNER, NC_O, 2>), dim3((NC_O/256)*2), dim3(512), 0, stream,
                       s2, V3, pO);
    hipLaunchKernelGGL((k_reduce<NC_H, 4>), dim3(B*NC_H/256), dim3(256), 0, stream,
                       pH, b3, h);
    hipLaunchKernelGGL((k_reduce<NC_O, 2>), dim3(B*NC_O/256), dim3(256), 0, stream,
                       pO, c3, ow);
    hipLaunchKernelGGL((k_softmax2<DIM, 3*INNER, 64, 4>), dim3(B*12), dim3(256), 0, stream, h);
    hipLaunchKernelGGL((k_softmax2<INNER, DIM, 32, 8>), dim3(B*4), dim3(256), 0, stream, ow);
    hipLaunchKernelGGL(k_proj, dim3(B*25), dim3(768), 0, stream, x, h, qh, kh, vt);
    hipLaunchKernelGGL(k_attn4, dim3(38*32), dim3(256), 0, stream, qh, kh, vt, mask, ao);
    hipLaunchKernelGGL(k_final, dim3(B*50), dim3(128), 0, stream, ao, ow, out);
}